// Round 5
// baseline (291.787 us; speedup 1.0000x reference)
//
#include <hip/hip_runtime.h>
#include <stdint.h>
#include <math.h>

// Problem shape (fixed by reference): xs [B,T,N,D] fp32, A [1,N,N] int32
#define BB 4
#define TT 32
#define NN 128
#define DD 32
#define NPB 16                       // nodes per block (16 nodes x 32 d = 512 threads)
#define TPB (NPB * DD)               // 512 threads
#define NBLK (BB * TT * (NN / NPB))  // 1024 blocks = exactly 4 per CU
#define CAP 16                       // band capacity incl temporal; overflow -> exact fallback
#define NK (CAP + 2)                 // 16 spatial slots + 2 temporal slots

// Arithmetic 8-bin partition of the value axis. ANY monotone non-decreasing
// bin function gives exact rank selection (equal values -> equal bins, so
// bins partition the multiset in value order). Median of ~66 N(0,1) lands in
// a bin with count <= CAP except ~1e-6/lane -> fallback is exact anyway.
__device__ __forceinline__ int bin8(float x) {
    int i = (int)fmaf(x, 5.0f, 4.0f);   // trunc; monotone non-decreasing
    i = i < 0 ? 0 : i;
    return i > 7 ? 7 : i;
}

// Adjacency row of each node as a 128-bit mask (A row nonzero | self loop).
__global__ __launch_bounds__(64) void build_adj_kernel(const int* __restrict__ A,
                                                       unsigned long long* __restrict__ mask) {
    const int n = blockIdx.x;
    const int lane = threadIdx.x;  // 0..63
    const int* arow = A + n * NN;
    const bool b0 = (arow[lane] != 0) || (lane == n);
    const bool b1 = (arow[lane + 64] != 0) || (lane + 64 == n);
    const unsigned long long m0 = __ballot(b0);
    const unsigned long long m1 = __ballot(b1);
    if (lane == 0) { mask[n * 2] = m0; mask[n * 2 + 1] = m1; }
}

// R5 = R4 minus LDS atomics (A/B test of the atomic-storm theory).
// R4's atomicOr scatter had ALL 64 lanes on banks {0,16} (32-way RMW
// conflict) -> LDS pipe saturation -> 250us, Occ 6.5%, VALUBusy 8%.
// Bitplane build is now OWNERSHIP-based: one writer per word,
// (bin-pair, d, word) = 4 reps x 32 d x 4 words = 512 = TPB. Each thread
// does 32 conflict-free sval reads (bank == d) + 2 plain stores. No
// zeroing pass needed (full overwrite). Everything else identical to R4:
//  - histogram = popcount(adj128 & binplane128): 8 ds_read_b128
//  - band extraction = ffs-walk of a 128-bit register mask
//  - ranking fully in registers (ki[18], all-pairs)
__global__ __launch_bounds__(TPB) void median_kernel(const float* __restrict__ xs,
                                                     const unsigned long long* __restrict__ mask,
                                                     float* __restrict__ out) {
    __shared__ __align__(16) float sval[NN * DD];           // 16 KB: current frame [n][d]
    __shared__ __align__(16) unsigned int sbit[8 * DD * 4]; // 4 KB: bitplanes [bin][d][n/32]

    const int tid = threadIdx.x;
    // Bijective XCD swizzle (NBLK % 8 == 0): contiguous logical chunk per XCD.
    const int bid = blockIdx.x;
    const int g = ((bid & 7) << 7) | (bid >> 3);
    const int ng = g & (NN / NPB - 1);       // % 8
    const int t  = (g >> 3) & (TT - 1);      // /8 % 32
    const int b  = g >> 8;                   // /256
    const int n0 = ng * NPB;

    const int d = tid & (DD - 1);
    const int nl = tid >> 5;  // local node 0..15
    const int n = n0 + nl;
    const int pv = (t > 0) ? 1 : 0;        // wave-uniform
    const int nv = (t < TT - 1) ? 1 : 0;   // wave-uniform
    const int ne = pv + nv;

    // temporal candidates (coalesced; issued before the barriers)
    float exv0 = 0.0f, exv1 = 0.0f;
    if (pv) exv0 = xs[(((size_t)(b * TT + t - 1) * NN) + n) * DD + d];
    if (nv) {
        float v = xs[(((size_t)(b * TT + t + 1) * NN) + n) * DD + d];
        if (pv) exv1 = v; else exv0 = v;
    }

    // stage current frame (float4 coalesced)
    const float4* src4 = (const float4*)(xs + ((size_t)(b * TT + t) * NN) * DD);
    const float4 f0 = src4[tid];
    const float4 f1 = src4[tid + 512];
    ((float4*)sval)[tid] = f0;
    ((float4*)sval)[tid + 512] = f1;

    __syncthreads();  // sval complete before bitplane build

    // ---- ownership-based bitplane build: thread (rep, wo, d) writes words
    // sbit[2*rep..2*rep+1][d][wo]. 32 sval reads, bank == d (2 lanes/bank,
    // free), all accumulation in registers, exactly one writer per word. ----
    {
        const int rep = tid >> 7;        // 0..3 -> bins {2r, 2r+1}
        const int wo  = (tid >> 5) & 3;  // word 0..3 -> nodes [wo*32, wo*32+32)
        const int ba = rep * 2, bc = rep * 2 + 1;
        uint32_t lo = 0u, hi = 0u;
        #pragma unroll 8
        for (int q = 0; q < 32; ++q) {
            const float v = sval[(wo * 32 + q) * DD + d];
            const int bv = bin8(v);
            lo |= (bv == ba) ? (1u << q) : 0u;
            hi |= (bv == bc) ? (1u << q) : 0u;
        }
        sbit[ba * 128 + d * 4 + wo] = lo;
        sbit[bc * 128 + d * 4 + wo] = hi;
    }
    __syncthreads();  // bitplanes visible

    // adjacency mask for this node (16B, broadcast across the 32 lanes of a node)
    const uint4 am4 = *((const uint4*)(mask + (size_t)n * 2));
    const unsigned int a0 = am4.x, a1 = am4.y, a2 = am4.z, a3 = am4.w;
    const unsigned long long am0 = (((unsigned long long)a1) << 32) | a0;
    const unsigned long long am1 = (((unsigned long long)a3) << 32) | a2;
    const int dg = __popcll(am0) + __popcll(am1);
    const int k = dg + ne;
    const uint32_t r = (uint32_t)((k - 1) >> 1);  // lower-median rank (0-based)
    const int be0 = bin8(exv0);
    const int be1 = bin8(exv1);
    const float INFV = __uint_as_float(0x7F800000u);

    // ---- histogram: 8 x (b128 read, AND, popcount-accumulate) ----
    int hist[8];
    const uint4* sbit4 = (const uint4*)sbit;
    #pragma unroll
    for (int bb = 0; bb < 8; ++bb) {
        uint4 w = sbit4[bb * 32 + d];
        hist[bb] = __popc(w.x & a0) + __popc(w.y & a1) + __popc(w.z & a2) + __popc(w.w & a3);
    }

    // ---- prefix over bins (temporal folded in statically); select rank bin ----
    uint32_t cum = 0, lowcnt = 0, mexp = 0;
    int selbin = -1;
    #pragma unroll
    for (int bb = 0; bb < 8; ++bb) {
        uint32_t bc = (uint32_t)hist[bb] + ((ne >= 1 && be0 == bb) ? 1u : 0u)
                                         + ((ne == 2 && be1 == bb) ? 1u : 0u);
        uint32_t nc = cum + bc;
        if (selbin < 0 && r < nc) { selbin = bb; lowcnt = cum; mexp = bc; }
        cum = nc;
    }
    const bool fb = (mexp > CAP);   // band too big -> exact fallback (~never)
    const uint32_t rp = r - lowcnt; // rank within band

    // ---- band mask: re-read selected bitplane (selbin is an address, not a
    // register index), AND with adjacency -> 128-bit register mask ----
    const int sb = fb ? 0 : selbin;
    uint4 ws = sbit4[sb * 32 + d];
    unsigned long long bm0 = (((unsigned long long)(ws.y & a1)) << 32) | (ws.x & a0);
    unsigned long long bm1 = (((unsigned long long)(ws.w & a3)) << 32) | (ws.z & a2);
    const int mc_sp = fb ? 0 : (__popcll(bm0) + __popcll(bm1));

    // ---- extract band values: static ffs-walk; sval bank == d (conflict-free) ----
    float ki[NK];
    #pragma unroll
    for (int u = 0; u < CAP; ++u) {
        const bool lo = (bm0 != 0ull);
        const unsigned long long mm_ = lo ? bm0 : bm1;
        const int ff = __ffsll((unsigned long long)mm_) - 1;  // -1 when empty
        const int id = ((lo ? ff : 64 + ff) & 127);
        const float v = sval[id * DD + d];
        ki[u] = (u < mc_sp) ? v : INFV;
        const unsigned long long cl = mm_ & (mm_ - 1ull);
        bm0 = lo ? cl : bm0;
        bm1 = lo ? bm1 : cl;
    }
    const bool t0 = (ne >= 1) && (be0 == selbin) && !fb;
    const bool t1 = (ne == 2) && (be1 == selbin) && !fb;
    ki[CAP]     = t0 ? exv0 : INFV;
    ki[CAP + 1] = t1 ? exv1 : INFV;

    // ---- rank within band: all-pairs strict-less, scalar count per slot ----
    // (INF slots contribute 0 to finite counts; invalid slots never selected)
    float result = 0.0f;
    bool found = fb;
    #pragma unroll
    for (int u = 0; u < NK; ++u) {
        uint32_t cnu = 0;
        #pragma unroll
        for (int v = 0; v < NK; ++v) cnu += (ki[v] < ki[u]) ? 1u : 0u;
        const bool valid = (u < CAP) ? (u < mc_sp) : ((u == CAP) ? t0 : t1);
        if (!found && valid && cnu == rp) { result = ki[u]; found = true; }
    }

    // ---- duplicate-median pass (exact multiset lower-median; ~never runs) ----
    if (__ballot(!found)) {
        #pragma unroll
        for (int u = 0; u < NK; ++u) {
            uint32_t cnu = 0, equ = 0;
            #pragma unroll
            for (int v = 0; v < NK; ++v) {
                cnu += (ki[v] < ki[u]) ? 1u : 0u;
                equ += (ki[v] == ki[u]) ? 1u : 0u;  // includes self
            }
            const bool valid = (u < CAP) ? (u < mc_sp) : ((u == CAP) ? t0 : t1);
            if (!found && valid && cnu <= rp && rp < cnu + equ) {
                result = ki[u]; found = true;
            }
        }
    }

    // ---- full fallback (band > CAP; ~1e-6 of lanes): exact over all k ----
    if (__ballot(fb)) {
        bool done = !fb;
        for (int i0 = 0; __ballot(!done && i0 < NN + 2); i0 += 8) {
            float k8[8]; uint32_t c8[8];
            #pragma unroll
            for (int u = 0; u < 8; ++u) {
                const int i = i0 + u;
                const unsigned long long src = (i < 64) ? am0 : am1;
                const bool memsp = ((src >> (i & 63)) & 1ull) != 0ull;
                const bool mem = (i < 128) ? memsp
                               : ((i == 128) ? (ne >= 1) : ((i == 129) ? (ne == 2) : false));
                const float v = (i < 128) ? sval[(i & 127) * DD + d]
                                          : ((i == 128) ? exv0 : exv1);
                k8[u] = mem ? v : INFV;
                c8[u] = 0;
            }
            for (int j = 0; j < NN; ++j) {
                const unsigned long long srcj = (j < 64) ? am0 : am1;
                const bool mj = ((srcj >> (j & 63)) & 1ull) != 0ull;
                const float x = mj ? sval[j * DD + d] : INFV;  // INF < k8 never true
                #pragma unroll
                for (int u = 0; u < 8; ++u) c8[u] += (x < k8[u]) ? 1u : 0u;
            }
            if (ne >= 1) {
                #pragma unroll
                for (int u = 0; u < 8; ++u) c8[u] += (exv0 < k8[u]) ? 1u : 0u;
            }
            if (ne == 2) {
                #pragma unroll
                for (int u = 0; u < 8; ++u) c8[u] += (exv1 < k8[u]) ? 1u : 0u;
            }
            #pragma unroll
            for (int u = 0; u < 8; ++u) {
                if (!done && k8[u] < INFV && c8[u] == r) { result = k8[u]; done = true; }
            }
        }
        if (__ballot(!done)) {  // duplicates across rank: exact multiset selection
            for (int i0 = 0; __ballot(!done && i0 < NN + 2); i0 += 4) {
                float k4[4]; uint32_t lt4[4], le4[4];
                #pragma unroll
                for (int u = 0; u < 4; ++u) {
                    const int i = i0 + u;
                    const unsigned long long src = (i < 64) ? am0 : am1;
                    const bool memsp = ((src >> (i & 63)) & 1ull) != 0ull;
                    const bool mem = (i < 128) ? memsp
                                   : ((i == 128) ? (ne >= 1) : ((i == 129) ? (ne == 2) : false));
                    const float v = (i < 128) ? sval[(i & 127) * DD + d]
                                              : ((i == 128) ? exv0 : exv1);
                    k4[u] = mem ? v : INFV;
                    lt4[u] = 0; le4[u] = 0;
                }
                for (int j = 0; j < NN; ++j) {
                    const unsigned long long srcj = (j < 64) ? am0 : am1;
                    const bool mj = ((srcj >> (j & 63)) & 1ull) != 0ull;
                    const float x = mj ? sval[j * DD + d] : INFV;
                    #pragma unroll
                    for (int u = 0; u < 4; ++u) {
                        lt4[u] += (x < k4[u]) ? 1u : 0u;
                        le4[u] += (x <= k4[u]) ? 1u : 0u;  // INF<=finite false
                    }
                }
                if (ne >= 1) {
                    #pragma unroll
                    for (int u = 0; u < 4; ++u) {
                        lt4[u] += (exv0 < k4[u]) ? 1u : 0u;
                        le4[u] += (exv0 <= k4[u]) ? 1u : 0u;
                    }
                }
                if (ne == 2) {
                    #pragma unroll
                    for (int u = 0; u < 4; ++u) {
                        lt4[u] += (exv1 < k4[u]) ? 1u : 0u;
                        le4[u] += (exv1 <= k4[u]) ? 1u : 0u;
                    }
                }
                #pragma unroll
                for (int u = 0; u < 4; ++u) {
                    if (!done && k4[u] < INFV && lt4[u] <= r && r < le4[u]) {
                        result = k4[u]; done = true;
                    }
                }
            }
        }
    }

    out[(((size_t)(b * TT + t) * NN) + n) * DD + d] = result;
}

extern "C" void kernel_launch(void* const* d_in, const int* in_sizes, int n_in,
                              void* d_out, int out_size, void* d_ws, size_t ws_size,
                              hipStream_t stream) {
    const float* xs = (const float*)d_in[0];
    const int* A = (const int*)d_in[1];
    float* out = (float*)d_out;

    // workspace layout: mask[128][2] u64 (2 KB)
    unsigned long long* mask = (unsigned long long*)d_ws;

    build_adj_kernel<<<NN, 64, 0, stream>>>(A, mask);
    median_kernel<<<NBLK, TPB, 0, stream>>>(xs, mask, out);
}

// Round 6
// 164.239 us; speedup vs baseline: 1.7766x; 1.7766x over previous
//
#include <hip/hip_runtime.h>
#include <stdint.h>
#include <math.h>

// Problem shape (fixed by reference): xs [B,T,N,D] fp32, A [1,N,N] int32
#define BB 4
#define TT 32
#define NN 128
#define DD 32
#define NPB 32                       // nodes per block (2 outputs/thread, 512 threads)
#define TPB 512
#define NBLK (BB * TT * (NN / NPB))  // 512 blocks x 8 waves = 4096 waves (was 8192)
#define CAP 16                       // band list capacity; selected-bin overflow -> exact fallback
#define SSTR (TPB + 4)               // 516: slist column stride (scatters banks across slots)

// Temporal-candidate sentinel ids in the u8 band list (real ids are 0..127).
#define SID_PREV 0xFEu
#define SID_NEXT 0xFFu

// Arithmetic 8-bin partition of the value axis. ANY monotone non-decreasing
// bin function gives exact rank selection (equal values -> equal bins, so
// bins partition the multiset in value order). Median of ~66 N(0,1) lands in
// a bin with count <= CAP except ~1e-5/lane -> fallback is exact anyway.
__device__ __forceinline__ int bin8(float x) {
    int i = (int)fmaf(x, 5.0f, 4.0f);   // trunc; monotone non-decreasing
    i = i < 0 ? 0 : i;
    return i > 7 ? 7 : i;
}

// Build per-node compacted neighbor lists from A (+ implicit self loop).
__global__ __launch_bounds__(64) void build_adj_kernel(const int* __restrict__ A,
                                                       int* __restrict__ deg,
                                                       uint8_t* __restrict__ nbr) {
    const int n = blockIdx.x;
    const int lane = threadIdx.x;  // 0..63
    const int* arow = A + n * NN;
    uint8_t* row = nbr + n * NN;
    const int j0 = lane, j1 = lane + 64;
    const bool b0 = (arow[j0] != 0) || (j0 == n);
    const bool b1 = (arow[j1] != 0) || (j1 == n);
    const unsigned long long m0 = __ballot(b0);
    const unsigned long long m1 = __ballot(b1);
    const unsigned long long lmask = (1ULL << lane) - 1ULL;
    const int c0 = __popcll(m0);
    if (b0) row[__popcll(m0 & lmask)] = (uint8_t)j0;
    if (b1) row[c0 + __popcll(m1 & lmask)] = (uint8_t)j1;
    if (lane == 0) deg[n] = c0 + __popcll(m1);
}

// R6: per-wave fixed-cost test. Session data: 8192 waves -> ~75us regardless
// of block size (R0: 2048x4w, R1/R3: 1024x8w), LDS size, instruction count,
// or bank conflicts; VALU-issue constant ~24us/SIMD; all throughput resources
// <1/3 of wall. Only surviving model: large fixed stall per wave. Test: SAME
// algorithm as R3 (known 76us), 2 outputs/thread -> 4096 waves. Bitset
// lineage (R4/R5, 250us) abandoned: regression unexplained after clean A/B.
__global__ __launch_bounds__(TPB) void median_kernel(const float* __restrict__ xs,
                                                     const int* __restrict__ deg,
                                                     const uint8_t* __restrict__ nbr,
                                                     float* __restrict__ out) {
    __shared__ float sval[NN * DD];             // 16 KB: current frame values
    __shared__ uint8_t sbin[NN * DD];           // 4 KB: per-element bin (0..7)
    __shared__ uint32_t snbr_w[NPB * NN / 4];   // 4 KB: neighbor id lists (u8)
    __shared__ int sdeg[NPB];
    __shared__ uint8_t slist[2 * (CAP + 1) * SSTR]; // 17.5 KB: 2 bands/thread, column-major

    const int tid = threadIdx.x;
    // Bijective XCD swizzle (NBLK % 8 == 0): each XCD gets a contiguous chunk
    // of 64 logical blocks -> frame re-reads are L2-local.
    const int bid = blockIdx.x;
    const int g = ((bid & 7) << 6) | (bid >> 3);
    const int ng = g & (NN / NPB - 1);       // % 4
    const int t  = (g >> 2) & (TT - 1);      // /4 % 32
    const int b  = g >> 7;                   // /128
    const int n0 = ng * NPB;

    const int d = tid & (DD - 1);
    const int nl = tid >> 5;  // local node 0..15; this thread owns nl and nl+16
    const int pv = (t > 0) ? 1 : 0;        // wave-uniform
    const int nv = (t < TT - 1) ? 1 : 0;   // wave-uniform
    const int ne = pv + nv;

    // temporal candidates for both owned nodes (coalesced; before the barrier)
    const int nA = n0 + nl;
    const int nB = n0 + nl + 16;
    float exv0A = 0.0f, exv1A = 0.0f, exv0B = 0.0f, exv1B = 0.0f;
    if (pv) {
        exv0A = xs[(((size_t)(b * TT + t - 1) * NN) + nA) * DD + d];
        exv0B = xs[(((size_t)(b * TT + t - 1) * NN) + nB) * DD + d];
    }
    if (nv) {
        float vA = xs[(((size_t)(b * TT + t + 1) * NN) + nA) * DD + d];
        float vB = xs[(((size_t)(b * TT + t + 1) * NN) + nB) * DD + d];
        if (pv) { exv1A = vA; exv1B = vB; } else { exv0A = vA; exv0B = vB; }
    }

    // stage current frame (float4 coalesced) + per-element bins (u32-packed)
    const float4* src4 = (const float4*)(xs + ((size_t)(b * TT + t) * NN) * DD);
    #pragma unroll
    for (int s = 0; s < 2; ++s) {
        int i4 = tid + (s << 9);
        float4 f = src4[i4];
        ((float4*)sval)[i4] = f;
        uint32_t pk = (uint32_t)bin8(f.x) | ((uint32_t)bin8(f.y) << 8)
                    | ((uint32_t)bin8(f.z) << 16) | ((uint32_t)bin8(f.w) << 24);
        ((uint32_t*)sbin)[i4] = pk;
    }
    // neighbor lists for 32 nodes: 1024 words / 512 threads = 2 each
    snbr_w[tid]       = ((const uint32_t*)(nbr + (size_t)n0 * NN))[tid];
    snbr_w[tid + 512] = ((const uint32_t*)(nbr + (size_t)n0 * NN))[tid + 512];
    if (tid < NPB) sdeg[tid] = deg[n0 + tid];
    __syncthreads();

    const float INFV = __uint_as_float(0x7F800000u);
    // per-element bin lookup: 1 byte (4-way banked; measured ~3us total cost)
    auto gbin = [&](uint32_t id) -> int { return (int)sbin[id * DD + d]; };

    for (int o = 0; o < 2; ++o) {
        const int nn_ = nl + (o << 4);        // local node 0..31
        const int n = n0 + nn_;
        const float exv0 = o ? exv0B : exv0A;
        const float exv1 = o ? exv1B : exv1A;
        const int dg = sdeg[nn_];
        const int k = dg + ne;
        const uint32_t r = (uint32_t)((k - 1) >> 1);  // lower-median rank (0-based)
        const uint8_t* nb = (const uint8_t*)snbr_w + nn_ * NN;
        uint8_t* sl = slist + (size_t)o * (CAP + 1) * SSTR;
        const int be0 = bin8(exv0);
        const int be1 = bin8(exv1);

        // ---- A1: one-pass 8-bin histogram, packed 8x8-bit in u64; unroll 8 ----
        unsigned long long pcnt = 0ull;
        {
            int j = 0;
            for (; j + 8 <= dg; j += 8) {
                uint32_t nw0 = *(const uint32_t*)(nb + j);
                uint32_t nw1 = *(const uint32_t*)(nb + j + 4);
                int bsv[8];
                #pragma unroll
                for (int q = 0; q < 4; ++q) {
                    bsv[q]     = gbin((nw0 >> (q * 8)) & 0xFFu);
                    bsv[q + 4] = gbin((nw1 >> (q * 8)) & 0xFFu);
                }
                #pragma unroll
                for (int q = 0; q < 8; ++q) pcnt += 1ull << (bsv[q] * 8);
            }
            for (; j < dg; ++j) pcnt += 1ull << (gbin(nb[j]) * 8);
            if (ne >= 1) pcnt += 1ull << (be0 * 8);
            if (ne == 2) pcnt += 1ull << (be1 * 8);
        }

        // ---- prefix over 8 byte-counts; select bin containing rank r ----
        uint32_t cum = 0, lowcnt = 0, mexp = 0;
        int selbin = -1;
        #pragma unroll
        for (int bb = 0; bb < 8; ++bb) {
            uint32_t bc = (uint32_t)(pcnt >> (bb * 8)) & 0xFFu;
            uint32_t nc = cum + bc;
            if (selbin < 0 && r < nc) { selbin = bb; lowcnt = cum; mexp = bc; }
            cum = nc;
        }
        const bool fb = (mexp > CAP);          // only fallback: band too big
        const uint32_t rp = r - lowcnt;        // rank within band
        const int storebin = fb ? -1 : selbin; // fb lanes store nothing (mc stays 0)

        // ---- A2: branchless compaction of band member IDS (always-store; the
        // member's write is always the last write to its slot before mc advances).
        // Bin bytes batched 8-deep into registers before the serial mc chain. ----
        int mc = 0;
        {
            int j = 0;
            for (; j + 8 <= dg; j += 8) {
                uint32_t nw0 = *(const uint32_t*)(nb + j);
                uint32_t nw1 = *(const uint32_t*)(nb + j + 4);
                uint32_t ids[8]; int bsv[8];
                #pragma unroll
                for (int q = 0; q < 4; ++q) {
                    ids[q]     = (nw0 >> (q * 8)) & 0xFFu;
                    ids[q + 4] = (nw1 >> (q * 8)) & 0xFFu;
                }
                #pragma unroll
                for (int q = 0; q < 8; ++q) bsv[q] = gbin(ids[q]);
                #pragma unroll
                for (int q = 0; q < 8; ++q) {
                    int slot = mc > CAP ? CAP : mc;
                    sl[slot * SSTR + tid] = (uint8_t)ids[q];
                    mc += (bsv[q] == storebin);
                }
            }
            for (; j < dg; ++j) {
                uint32_t id = nb[j];
                int bv = gbin(id);
                int slot = mc > CAP ? CAP : mc;
                sl[slot * SSTR + tid] = (uint8_t)id;
                mc += (bv == storebin);
            }
            if (ne >= 1) {
                int slot = mc > CAP ? CAP : mc;
                sl[slot * SSTR + tid] = (uint8_t)SID_PREV;
                mc += (be0 == storebin);
            }
            if (ne == 2) {
                int slot = mc > CAP ? CAP : mc;
                sl[slot * SSTR + tid] = (uint8_t)SID_NEXT;
                mc += (be1 == storebin);
            }
        }

        // band value fetch: id & 127 keeps even garbage/sentinel ids in-bounds;
        // sentinels override via cndmask. sl column tid is thread-private, so
        // no barrier needed between A2 writes and these reads.
        auto bandval = [&](int e) -> float {
            uint32_t id = sl[e * SSTR + tid];
            float v = sval[(id & 127u) * DD + d];
            v = (id == SID_PREV) ? exv0 : v;
            v = (id == SID_NEXT) ? exv1 : v;
            return v;
        };

        // ---- B: single W=16 counting pass over the band (mc <= CAP) ----
        float ki[CAP];
        uint32_t cn[CAP];
        #pragma unroll
        for (int u = 0; u < CAP; ++u) {
            float v = bandval(u);
            ki[u] = (u < mc) ? v : INFV;
            cn[u] = 0;
        }
        int mm = mc;  // wave max -> uniform trip count
        #pragma unroll
        for (int off = 32; off; off >>= 1) {
            int oo = __shfl_xor(mm, off);
            mm = mm > oo ? mm : oo;
        }
        {
            int j = 0;
            for (; j + 2 <= mm; j += 2) {  // unroll 2: two independent LDS chains
                float x0 = bandval(j);
                float x1 = bandval(j + 1);
                x0 = (j < mc) ? x0 : INFV;      // INF < ki never true
                x1 = (j + 1 < mc) ? x1 : INFV;
                #pragma unroll
                for (int u = 0; u < CAP; ++u) cn[u] += (x0 < ki[u]) + (x1 < ki[u]);
            }
            if (j < mm) {
                float x = bandval(j);
                x = (j < mc) ? x : INFV;
                #pragma unroll
                for (int u = 0; u < CAP; ++u) cn[u] += (x < ki[u]);
            }
        }
        float result = 0.0f;
        bool found = fb;
        #pragma unroll
        for (int u = 0; u < CAP; ++u) {
            // strict-below count == rp identifies rank-rp exactly (unique per value)
            if (!found && u < mc && cn[u] == rp) { result = ki[u]; found = true; }
        }

        // ---- duplicate-median pass (exact multiset lower-median; ~never runs) ----
        if (__ballot(!found)) {
            uint32_t eq[CAP];
            #pragma unroll
            for (int u = 0; u < CAP; ++u) eq[u] = 0;
            for (int j = 0; j < mm; ++j) {
                float x = bandval(j);
                x = (j < mc) ? x : INFV;  // INF == finite ki is false
                #pragma unroll
                for (int u = 0; u < CAP; ++u) eq[u] += (x == ki[u]);
            }
            #pragma unroll
            for (int u = 0; u < CAP; ++u) {
                if (!found && u < mc && cn[u] <= rp && rp < cn[u] + eq[u]) {
                    result = ki[u]; found = true;
                }
            }
        }

        // ---- full fallback (band > CAP; ~1e-5 of lanes): exact over all k ----
        if (__ballot(fb)) {
            bool done = !fb;
            for (int i0 = 0; __ballot(!done && i0 < k); i0 += 8) {
                float k8[8]; uint32_t c8[8];
                #pragma unroll
                for (int u = 0; u < 8; ++u) {
                    int i = i0 + u;
                    float sv = sval[nb[i & 127] * DD + d];
                    float ev = ((i - dg) == 0) ? exv0 : exv1;
                    float v = (i < dg) ? sv : ev;
                    k8[u] = (i < k) ? v : INFV;
                    c8[u] = 0;
                }
                for (int j = 0; j < dg; ++j) {
                    float xv = sval[nb[j] * DD + d];
                    #pragma unroll
                    for (int u = 0; u < 8; ++u) c8[u] += (xv < k8[u]);
                }
                if (ne >= 1) {
                    #pragma unroll
                    for (int u = 0; u < 8; ++u) c8[u] += (exv0 < k8[u]);
                }
                if (ne == 2) {
                    #pragma unroll
                    for (int u = 0; u < 8; ++u) c8[u] += (exv1 < k8[u]);
                }
                #pragma unroll
                for (int u = 0; u < 8; ++u) {
                    if (!done && (i0 + u) < k && c8[u] == r) { result = k8[u]; done = true; }
                }
            }
            if (__ballot(!done)) {  // duplicates across rank: exact multiset selection
                for (int i0 = 0; __ballot(!done && i0 < k); i0 += 4) {
                    float k4[4]; uint32_t lt4[4], le4[4];
                    #pragma unroll
                    for (int u = 0; u < 4; ++u) {
                        int i = i0 + u;
                        float sv = sval[nb[i & 127] * DD + d];
                        float ev = ((i - dg) == 0) ? exv0 : exv1;
                        float v = (i < dg) ? sv : ev;
                        k4[u] = (i < k) ? v : INFV;
                        lt4[u] = 0; le4[u] = 0;
                    }
                    for (int j = 0; j < dg; ++j) {
                        float xv = sval[nb[j] * DD + d];
                        #pragma unroll
                        for (int u = 0; u < 4; ++u) { lt4[u] += (xv < k4[u]); le4[u] += (xv <= k4[u]); }
                    }
                    if (ne >= 1) {
                        #pragma unroll
                        for (int u = 0; u < 4; ++u) { lt4[u] += (exv0 < k4[u]); le4[u] += (exv0 <= k4[u]); }
                    }
                    if (ne == 2) {
                        #pragma unroll
                        for (int u = 0; u < 4; ++u) { lt4[u] += (exv1 < k4[u]); le4[u] += (exv1 <= k4[u]); }
                    }
                    #pragma unroll
                    for (int u = 0; u < 4; ++u) {
                        if (!done && (i0 + u) < k && lt4[u] <= r && r < le4[u]) {
                            result = k4[u]; done = true;
                        }
                    }
                }
            }
        }

        out[(((size_t)(b * TT + t) * NN) + n) * DD + d] = result;
    }
}

extern "C" void kernel_launch(void* const* d_in, const int* in_sizes, int n_in,
                              void* d_out, int out_size, void* d_ws, size_t ws_size,
                              hipStream_t stream) {
    const float* xs = (const float*)d_in[0];
    const int* A = (const int*)d_in[1];
    float* out = (float*)d_out;

    // workspace layout: deg[128] int (512 B) | nbr[128][128] u8 (16 KB)
    int* deg = (int*)d_ws;
    uint8_t* nbr = (uint8_t*)d_ws + 512;

    build_adj_kernel<<<NN, 64, 0, stream>>>(A, deg, nbr);
    median_kernel<<<NBLK, TPB, 0, stream>>>(xs, deg, nbr, out);
}

// Round 7
// 121.271 us; speedup vs baseline: 2.4061x; 1.3543x over previous
//
#include <hip/hip_runtime.h>
#include <stdint.h>
#include <math.h>

// Problem shape (fixed by reference): xs [B,T,N,D] fp32, A [1,N,N] int32
#define BB 4
#define TT 32
#define NN 128
#define DD 32
#define NPB 16                       // nodes per block (16 nodes x 32 d = 512 threads)
#define TPB (NPB * DD)               // 512 threads
#define NBLK (BB * TT * (NN / NPB))  // 1024 blocks = exactly 4 per CU
#define CAP 16                       // band list capacity; selected-bin overflow -> exact fallback
#define SSTR (TPB + 4)               // 516: slist column stride (scatters banks across slots)

// Temporal-candidate sentinel ids in the u8 band list (real ids are 0..127).
#define SID_PREV 0xFEu
#define SID_NEXT 0xFFu

// Arithmetic 8-bin partition of the value axis. ANY monotone non-decreasing
// bin function gives exact rank selection (equal values -> equal bins, so
// bins partition the multiset in value order). Median of ~66 N(0,1) lands in
// a bin with count <= CAP except ~1e-5/lane -> fallback is exact anyway.
__device__ __forceinline__ int bin8(float x) {
    int i = (int)fmaf(x, 5.0f, 4.0f);   // trunc; monotone non-decreasing
    i = i < 0 ? 0 : i;
    return i > 7 ? 7 : i;
}

// R7: FUSION. Score anatomy across the session: dur_us - median_dispatch ~=
// 45-50us EVERY round (build_adj dispatch + inter-kernel gap + ws handling)
// -- 38% of the score, untouched until now. This round: exact R3 body
// (best dispatch, 76us), with adjacency computed IN-BLOCK (one wave ballots
// 2 rows of A, same popcount compaction as the old build_adj; A is 64KB,
// L2-resident). Single kernel launch, d_ws unused. R6's 2-outputs/thread
// reverted (112us: halving waves hurt -- structure is latency-bound, more
// TLP helps; VALU-issue/SIMD constant ~25us across R0/R1/R3/R6).
__global__ __launch_bounds__(TPB) void median_kernel(const float* __restrict__ xs,
                                                     const int* __restrict__ A,
                                                     float* __restrict__ out) {
    __shared__ float sval[NN * DD];             // 16 KB: current frame values
    __shared__ uint8_t sbin[NN * DD];           // 4 KB: per-element bin (0..7)
    __shared__ uint32_t snbr_w[NPB * NN / 4];   // 2 KB: neighbor id lists (u8)
    __shared__ int sdeg[NPB];
    __shared__ uint8_t slist[(CAP + 1) * SSTR]; // 8.8 KB: band member IDS, column-major

    const int tid = threadIdx.x;
    // Bijective XCD swizzle (NBLK % 8 == 0): each XCD gets a contiguous chunk
    // of 128 logical blocks = 16 whole frames -> frame re-reads are L2-local.
    const int bid = blockIdx.x;
    const int g = ((bid & 7) << 7) | (bid >> 3);
    const int ng = g & (NN / NPB - 1);       // % 8
    const int t  = (g >> 3) & (TT - 1);      // /8 % 32
    const int b  = g >> 8;                   // /256
    const int n0 = ng * NPB;

    const int d = tid & (DD - 1);
    const int nl = tid >> 5;  // local node 0..15
    const int n = n0 + nl;
    const int pv = (t > 0) ? 1 : 0;        // wave-uniform
    const int nv = (t < TT - 1) ? 1 : 0;   // wave-uniform
    const int ne = pv + nv;

    // temporal candidates as floats (coalesced; issued before the barrier)
    float exv0 = 0.0f, exv1 = 0.0f;
    if (pv) exv0 = xs[(((size_t)(b * TT + t - 1) * NN) + n) * DD + d];
    if (nv) {
        float v = xs[(((size_t)(b * TT + t + 1) * NN) + n) * DD + d];
        if (pv) exv1 = v; else exv0 = v;
    }

    // stage current frame (float4 coalesced) + per-element bins (u32-packed)
    const float4* src4 = (const float4*)(xs + ((size_t)(b * TT + t) * NN) * DD);
    #pragma unroll
    for (int s = 0; s < 2; ++s) {
        int i4 = tid + (s << 9);
        float4 f = src4[i4];
        ((float4*)sval)[i4] = f;
        uint32_t pk = (uint32_t)bin8(f.x) | ((uint32_t)bin8(f.y) << 8)
                    | ((uint32_t)bin8(f.z) << 16) | ((uint32_t)bin8(f.w) << 24);
        ((uint32_t*)sbin)[i4] = pk;
    }

    // ---- fused adjacency build: wave wid ballots rows 2*wid, 2*wid+1 of A
    // (+ implicit self loop) into compacted u8 lists. A is 64KB, L2-resident.
    {
        uint8_t* snbr = (uint8_t*)snbr_w;
        const int lane = tid & 63;
        const int wid = tid >> 6;  // 0..7
        const unsigned long long lmask = (1ULL << lane) - 1ULL;
        #pragma unroll
        for (int h = 0; h < 2; ++h) {
            const int rr = wid * 2 + h;          // local row 0..15
            const int nrow = n0 + rr;            // global node id
            const int* arow = A + nrow * NN;
            const bool b0 = (arow[lane] != 0) || (lane == nrow);
            const bool b1 = (arow[lane + 64] != 0) || (lane + 64 == nrow);
            const unsigned long long m0 = __ballot(b0);
            const unsigned long long m1 = __ballot(b1);
            const int c0 = __popcll(m0);
            if (b0) snbr[rr * NN + __popcll(m0 & lmask)] = (uint8_t)lane;
            if (b1) snbr[rr * NN + c0 + __popcll(m1 & lmask)] = (uint8_t)(lane + 64);
            if (lane == 0) sdeg[rr] = c0 + __popcll(m1);
        }
    }
    __syncthreads();

    const int dg = sdeg[nl];
    const int k = dg + ne;
    const uint32_t r = (uint32_t)((k - 1) >> 1);  // lower-median rank (0-based)
    const uint8_t* nb = (const uint8_t*)snbr_w + nl * NN;
    const float INFV = __uint_as_float(0x7F800000u);

    // per-element bin lookup: 1 byte, ~4-way banked
    auto gbin = [&](uint32_t id) -> int { return (int)sbin[id * DD + d]; };
    const int be0 = bin8(exv0);
    const int be1 = bin8(exv1);

    // ---- A1: one-pass 8-bin histogram, packed 8x8-bit in u64; unroll 8 ----
    unsigned long long pcnt = 0ull;
    {
        int j = 0;
        for (; j + 8 <= dg; j += 8) {
            uint32_t nw0 = *(const uint32_t*)(nb + j);
            uint32_t nw1 = *(const uint32_t*)(nb + j + 4);
            int bsv[8];
            #pragma unroll
            for (int q = 0; q < 4; ++q) {
                bsv[q]     = gbin((nw0 >> (q * 8)) & 0xFFu);
                bsv[q + 4] = gbin((nw1 >> (q * 8)) & 0xFFu);
            }
            #pragma unroll
            for (int q = 0; q < 8; ++q) pcnt += 1ull << (bsv[q] * 8);
        }
        for (; j < dg; ++j) pcnt += 1ull << (gbin(nb[j]) * 8);
        if (ne >= 1) pcnt += 1ull << (be0 * 8);
        if (ne == 2) pcnt += 1ull << (be1 * 8);
    }

    // ---- prefix over 8 byte-counts; select bin containing rank r ----
    uint32_t cum = 0, lowcnt = 0, mexp = 0;
    int selbin = -1;
    #pragma unroll
    for (int bb = 0; bb < 8; ++bb) {
        uint32_t bc = (uint32_t)(pcnt >> (bb * 8)) & 0xFFu;
        uint32_t nc = cum + bc;
        if (selbin < 0 && r < nc) { selbin = bb; lowcnt = cum; mexp = bc; }
        cum = nc;
    }
    const bool fb = (mexp > CAP);          // only fallback: band too big
    const uint32_t rp = r - lowcnt;        // rank within band
    const int storebin = fb ? -1 : selbin; // fb lanes store nothing (mc stays 0)

    // ---- A2: branchless compaction of band member IDS (always-store; the
    // member's write is always the last write to its slot before mc advances).
    // Bin bytes batched 8-deep into registers before the serial mc chain. ----
    int mc = 0;
    {
        int j = 0;
        for (; j + 8 <= dg; j += 8) {
            uint32_t nw0 = *(const uint32_t*)(nb + j);
            uint32_t nw1 = *(const uint32_t*)(nb + j + 4);
            uint32_t ids[8]; int bsv[8];
            #pragma unroll
            for (int q = 0; q < 4; ++q) {
                ids[q]     = (nw0 >> (q * 8)) & 0xFFu;
                ids[q + 4] = (nw1 >> (q * 8)) & 0xFFu;
            }
            #pragma unroll
            for (int q = 0; q < 8; ++q) bsv[q] = gbin(ids[q]);
            #pragma unroll
            for (int q = 0; q < 8; ++q) {
                int slot = mc > CAP ? CAP : mc;
                slist[slot * SSTR + tid] = (uint8_t)ids[q];
                mc += (bsv[q] == storebin);
            }
        }
        for (; j < dg; ++j) {
            uint32_t id = nb[j];
            int bv = gbin(id);
            int slot = mc > CAP ? CAP : mc;
            slist[slot * SSTR + tid] = (uint8_t)id;
            mc += (bv == storebin);
        }
        if (ne >= 1) {
            int slot = mc > CAP ? CAP : mc;
            slist[slot * SSTR + tid] = (uint8_t)SID_PREV;
            mc += (be0 == storebin);
        }
        if (ne == 2) {
            int slot = mc > CAP ? CAP : mc;
            slist[slot * SSTR + tid] = (uint8_t)SID_NEXT;
            mc += (be1 == storebin);
        }
    }

    // band value fetch: id & 127 keeps even garbage/sentinel ids in-bounds;
    // sentinels override via cndmask. slist column tid is thread-private, so
    // no barrier needed between A2 writes and these reads (same-thread lgkmcnt).
    auto bandval = [&](int e) -> float {
        uint32_t id = slist[e * SSTR + tid];
        float v = sval[(id & 127u) * DD + d];
        v = (id == SID_PREV) ? exv0 : v;
        v = (id == SID_NEXT) ? exv1 : v;
        return v;
    };

    // ---- B: single W=16 counting pass over the band (mc <= CAP) ----
    float ki[CAP];
    uint32_t cn[CAP];
    #pragma unroll
    for (int u = 0; u < CAP; ++u) {
        float v = bandval(u);
        ki[u] = (u < mc) ? v : INFV;
        cn[u] = 0;
    }
    int mm = mc;  // wave max -> uniform trip count
    #pragma unroll
    for (int off = 32; off; off >>= 1) {
        int o = __shfl_xor(mm, off);
        mm = mm > o ? mm : o;
    }
    {
        int j = 0;
        for (; j + 2 <= mm; j += 2) {  // unroll 2: two independent LDS chains
            float x0 = bandval(j);
            float x1 = bandval(j + 1);
            x0 = (j < mc) ? x0 : INFV;      // INF < ki never true
            x1 = (j + 1 < mc) ? x1 : INFV;
            #pragma unroll
            for (int u = 0; u < CAP; ++u) cn[u] += (x0 < ki[u]) + (x1 < ki[u]);
        }
        if (j < mm) {
            float x = bandval(j);
            x = (j < mc) ? x : INFV;
            #pragma unroll
            for (int u = 0; u < CAP; ++u) cn[u] += (x < ki[u]);
        }
    }
    float result = 0.0f;
    bool found = fb;
    #pragma unroll
    for (int u = 0; u < CAP; ++u) {
        // strict-below count == rp identifies rank-rp exactly (unique per value)
        if (!found && u < mc && cn[u] == rp) { result = ki[u]; found = true; }
    }

    // ---- duplicate-median pass (exact multiset lower-median; ~never runs) ----
    if (__ballot(!found)) {
        uint32_t eq[CAP];
        #pragma unroll
        for (int u = 0; u < CAP; ++u) eq[u] = 0;
        for (int j = 0; j < mm; ++j) {
            float x = bandval(j);
            x = (j < mc) ? x : INFV;  // INF == finite ki is false
            #pragma unroll
            for (int u = 0; u < CAP; ++u) eq[u] += (x == ki[u]);
        }
        #pragma unroll
        for (int u = 0; u < CAP; ++u) {
            if (!found && u < mc && cn[u] <= rp && rp < cn[u] + eq[u]) {
                result = ki[u]; found = true;
            }
        }
    }

    // ---- full fallback (band > CAP; ~1e-5 of lanes): exact over all k ----
    if (__ballot(fb)) {
        bool done = !fb;
        for (int i0 = 0; __ballot(!done && i0 < k); i0 += 8) {
            float k8[8]; uint32_t c8[8];
            #pragma unroll
            for (int u = 0; u < 8; ++u) {
                int i = i0 + u;
                float sv = sval[nb[i & 127] * DD + d];
                float ev = ((i - dg) == 0) ? exv0 : exv1;
                float v = (i < dg) ? sv : ev;
                k8[u] = (i < k) ? v : INFV;
                c8[u] = 0;
            }
            for (int j = 0; j < dg; ++j) {
                float xv = sval[nb[j] * DD + d];
                #pragma unroll
                for (int u = 0; u < 8; ++u) c8[u] += (xv < k8[u]);
            }
            if (ne >= 1) {
                #pragma unroll
                for (int u = 0; u < 8; ++u) c8[u] += (exv0 < k8[u]);
            }
            if (ne == 2) {
                #pragma unroll
                for (int u = 0; u < 8; ++u) c8[u] += (exv1 < k8[u]);
            }
            #pragma unroll
            for (int u = 0; u < 8; ++u) {
                if (!done && (i0 + u) < k && c8[u] == r) { result = k8[u]; done = true; }
            }
        }
        if (__ballot(!done)) {  // duplicates across rank: exact multiset selection
            for (int i0 = 0; __ballot(!done && i0 < k); i0 += 4) {
                float k4[4]; uint32_t lt4[4], le4[4];
                #pragma unroll
                for (int u = 0; u < 4; ++u) {
                    int i = i0 + u;
                    float sv = sval[nb[i & 127] * DD + d];
                    float ev = ((i - dg) == 0) ? exv0 : exv1;
                    float v = (i < dg) ? sv : ev;
                    k4[u] = (i < k) ? v : INFV;
                    lt4[u] = 0; le4[u] = 0;
                }
                for (int j = 0; j < dg; ++j) {
                    float xv = sval[nb[j] * DD + d];
                    #pragma unroll
                    for (int u = 0; u < 4; ++u) { lt4[u] += (xv < k4[u]); le4[u] += (xv <= k4[u]); }
                }
                if (ne >= 1) {
                    #pragma unroll
                    for (int u = 0; u < 4; ++u) { lt4[u] += (exv0 < k4[u]); le4[u] += (exv0 <= k4[u]); }
                }
                if (ne == 2) {
                    #pragma unroll
                    for (int u = 0; u < 4; ++u) { lt4[u] += (exv1 < k4[u]); le4[u] += (exv1 <= k4[u]); }
                }
                #pragma unroll
                for (int u = 0; u < 4; ++u) {
                    if (!done && (i0 + u) < k && lt4[u] <= r && r < le4[u]) {
                        result = k4[u]; done = true;
                    }
                }
            }
        }
    }

    out[(((size_t)(b * TT + t) * NN) + n) * DD + d] = result;
}

extern "C" void kernel_launch(void* const* d_in, const int* in_sizes, int n_in,
                              void* d_out, int out_size, void* d_ws, size_t ws_size,
                              hipStream_t stream) {
    const float* xs = (const float*)d_in[0];
    const int* A = (const int*)d_in[1];
    float* out = (float*)d_out;
    (void)d_ws; (void)ws_size;  // no workspace: adjacency fused into the kernel

    median_kernel<<<NBLK, TPB, 0, stream>>>(xs, A, out);
}

// Round 9
// 120.628 us; speedup vs baseline: 2.4189x; 1.0053x over previous
//
#include <hip/hip_runtime.h>
#include <stdint.h>
#include <math.h>

// Problem shape (fixed by reference): xs [B,T,N,D] fp32, A [1,N,N] int32
#define BB 4
#define TT 32
#define NN 128
#define DD 32
#define NPB 16                       // nodes per block (16 nodes x 32 d = 512 threads)
#define TPB (NPB * DD)               // 512 threads
#define NBLK (BB * TT * (NN / NPB))  // 1024 blocks = exactly 4 per CU
#define CAP 16                       // band list capacity; selected-bin overflow -> exact fallback
#define SSTR (TPB + 4)               // 516: slist column stride (scatters banks across slots)

// Temporal-candidate sentinel ids in the u8 band list (real ids are 0..127).
#define SID_PREV 0xFEu
#define SID_NEXT 0xFFu

// Arithmetic 8-bin partition of the value axis. ANY monotone non-decreasing
// bin function gives exact rank selection (equal values -> equal bins, so
// bins partition the multiset in value order). Median of ~66 N(0,1) lands in
// a bin with count <= CAP except ~1e-5/lane -> fallback is exact anyway.
__device__ __forceinline__ int bin8(float x) {
    int i = (int)fmaf(x, 5.0f, 4.0f);   // trunc; monotone non-decreasing
    i = i < 0 ? 0 : i;
    return i > 7 ? 7 : i;
}

// R9 == R8 resubmit (R8 bench was an infra failure, no data; R2 precedent:
// identical source passed on resubmit). Controlled bisection of the R4/R5
// bitset mystery (those ran 250us with FEWER LDS ops and SAME VALU --
// unexplained). This kernel = R7 verbatim EXCEPT A1: the 83-LDS-read
// histogram scan is replaced by the bitplane histogram (8 x ds_read_b128 +
// popcount vs adjacency masks). Bitplanes are built from sbin by the R5
// ownership method (no atomics, one writer/word). A2 (serial compaction),
// B, dup, fallback, slist, grid: byte-identical R7.
// Healthy -> ~67-73us dispatch and the R4 curse lives in the ffs-walk/pairs;
// sick (>=150us) -> bitplanes themselves are the cursed piece, abandon.
__global__ __launch_bounds__(TPB) void median_kernel(const float* __restrict__ xs,
                                                     const int* __restrict__ A,
                                                     float* __restrict__ out) {
    __shared__ float sval[NN * DD];             // 16 KB: current frame values
    __shared__ uint8_t sbin[NN * DD];           // 4 KB: per-element bin (0..7)
    __shared__ __align__(16) uint32_t sbit[8 * DD * 4]; // 4 KB: bitplanes [bin][d][n/32]
    __shared__ uint32_t snbr_w[NPB * NN / 4];   // 2 KB: neighbor id lists (u8)
    __shared__ __align__(16) uint32_t smask[NPB][4];    // 256 B: adjacency masks
    __shared__ int sdeg[NPB];
    __shared__ uint8_t slist[(CAP + 1) * SSTR]; // 8.8 KB: band member IDS, column-major

    const int tid = threadIdx.x;
    // Bijective XCD swizzle (NBLK % 8 == 0): each XCD gets a contiguous chunk
    // of 128 logical blocks = 16 whole frames -> frame re-reads are L2-local.
    const int bid = blockIdx.x;
    const int g = ((bid & 7) << 7) | (bid >> 3);
    const int ng = g & (NN / NPB - 1);       // % 8
    const int t  = (g >> 3) & (TT - 1);      // /8 % 32
    const int b  = g >> 8;                   // /256
    const int n0 = ng * NPB;

    const int d = tid & (DD - 1);
    const int nl = tid >> 5;  // local node 0..15
    const int n = n0 + nl;
    const int pv = (t > 0) ? 1 : 0;        // wave-uniform
    const int nv = (t < TT - 1) ? 1 : 0;   // wave-uniform
    const int ne = pv + nv;

    // temporal candidates as floats (coalesced; issued before the barrier)
    float exv0 = 0.0f, exv1 = 0.0f;
    if (pv) exv0 = xs[(((size_t)(b * TT + t - 1) * NN) + n) * DD + d];
    if (nv) {
        float v = xs[(((size_t)(b * TT + t + 1) * NN) + n) * DD + d];
        if (pv) exv1 = v; else exv0 = v;
    }

    // stage current frame (float4 coalesced) + per-element bins (u32-packed)
    const float4* src4 = (const float4*)(xs + ((size_t)(b * TT + t) * NN) * DD);
    #pragma unroll
    for (int s = 0; s < 2; ++s) {
        int i4 = tid + (s << 9);
        float4 f = src4[i4];
        ((float4*)sval)[i4] = f;
        uint32_t pk = (uint32_t)bin8(f.x) | ((uint32_t)bin8(f.y) << 8)
                    | ((uint32_t)bin8(f.z) << 16) | ((uint32_t)bin8(f.w) << 24);
        ((uint32_t*)sbin)[i4] = pk;
    }

    // ---- fused adjacency build: wave wid ballots rows 2*wid, 2*wid+1 of A
    // (+ implicit self loop) into compacted u8 lists AND raw mask words.
    {
        uint8_t* snbr = (uint8_t*)snbr_w;
        const int lane = tid & 63;
        const int wid = tid >> 6;  // 0..7
        const unsigned long long lmask = (1ULL << lane) - 1ULL;
        #pragma unroll
        for (int h = 0; h < 2; ++h) {
            const int rr = wid * 2 + h;          // local row 0..15
            const int nrow = n0 + rr;            // global node id
            const int* arow = A + nrow * NN;
            const bool b0 = (arow[lane] != 0) || (lane == nrow);
            const bool b1 = (arow[lane + 64] != 0) || (lane + 64 == nrow);
            const unsigned long long m0 = __ballot(b0);
            const unsigned long long m1 = __ballot(b1);
            const int c0 = __popcll(m0);
            if (b0) snbr[rr * NN + __popcll(m0 & lmask)] = (uint8_t)lane;
            if (b1) snbr[rr * NN + c0 + __popcll(m1 & lmask)] = (uint8_t)(lane + 64);
            if (lane == 0) {
                sdeg[rr] = c0 + __popcll(m1);
                smask[rr][0] = (uint32_t)m0;
                smask[rr][1] = (uint32_t)(m0 >> 32);
                smask[rr][2] = (uint32_t)m1;
                smask[rr][3] = (uint32_t)(m1 >> 32);
            }
        }
    }
    __syncthreads();  // sval/sbin/snbr/smask ready

    // ---- ownership bitplane build (R5 method): thread (rep, wo, dd) owns
    // words sbit[2rep..2rep+1][dd][wo]; 32 sbin byte reads, regs, 2 stores.
    {
        const int rep = tid >> 7;        // 0..3 -> bins {2r, 2r+1}
        const int wo  = (tid >> 5) & 3;  // word 0..3 -> nodes [wo*32, wo*32+32)
        const int dd  = tid & 31;
        const int ba = rep * 2, bc = ba + 1;
        uint32_t lo = 0u, hi = 0u;
        #pragma unroll 8
        for (int q = 0; q < 32; ++q) {
            const int bv = (int)sbin[(wo * 32 + q) * DD + dd];
            lo |= (bv == ba) ? (1u << q) : 0u;
            hi |= (bv == bc) ? (1u << q) : 0u;
        }
        sbit[ba * 128 + dd * 4 + wo] = lo;
        sbit[bc * 128 + dd * 4 + wo] = hi;
    }
    __syncthreads();  // bitplanes visible

    const int dg = sdeg[nl];
    const int k = dg + ne;
    const uint32_t r = (uint32_t)((k - 1) >> 1);  // lower-median rank (0-based)
    const uint8_t* nb = (const uint8_t*)snbr_w + nl * NN;
    const float INFV = __uint_as_float(0x7F800000u);

    // per-element bin lookup: 1 byte, ~4-way banked (used by A2 only now)
    auto gbin = [&](uint32_t id) -> int { return (int)sbin[id * DD + d]; };
    const int be0 = bin8(exv0);
    const int be1 = bin8(exv1);

    // ---- A1 (NEW): bitplane histogram -- 8 x (b128 read, AND, popcount) ----
    const uint4 am4 = *((const uint4*)smask[nl]);  // broadcast within node-group
    int hist[8];
    const uint4* sbit4 = (const uint4*)sbit;
    #pragma unroll
    for (int bb = 0; bb < 8; ++bb) {
        uint4 w = sbit4[bb * 32 + d];
        hist[bb] = __popc(w.x & am4.x) + __popc(w.y & am4.y)
                 + __popc(w.z & am4.z) + __popc(w.w & am4.w);
    }

    // ---- prefix over bins (temporal folded in); select bin containing r ----
    uint32_t cum = 0, lowcnt = 0, mexp = 0;
    int selbin = -1;
    #pragma unroll
    for (int bb = 0; bb < 8; ++bb) {
        uint32_t bc = (uint32_t)hist[bb] + ((ne >= 1 && be0 == bb) ? 1u : 0u)
                                         + ((ne == 2 && be1 == bb) ? 1u : 0u);
        uint32_t nc = cum + bc;
        if (selbin < 0 && r < nc) { selbin = bb; lowcnt = cum; mexp = bc; }
        cum = nc;
    }
    const bool fb = (mexp > CAP);          // only fallback: band too big
    const uint32_t rp = r - lowcnt;        // rank within band
    const int storebin = fb ? -1 : selbin; // fb lanes store nothing (mc stays 0)

    // ---- A2: branchless compaction of band member IDS (always-store; the
    // member's write is always the last write to its slot before mc advances).
    // Bin bytes batched 8-deep into registers before the serial mc chain. ----
    int mc = 0;
    {
        int j = 0;
        for (; j + 8 <= dg; j += 8) {
            uint32_t nw0 = *(const uint32_t*)(nb + j);
            uint32_t nw1 = *(const uint32_t*)(nb + j + 4);
            uint32_t ids[8]; int bsv[8];
            #pragma unroll
            for (int q = 0; q < 4; ++q) {
                ids[q]     = (nw0 >> (q * 8)) & 0xFFu;
                ids[q + 4] = (nw1 >> (q * 8)) & 0xFFu;
            }
            #pragma unroll
            for (int q = 0; q < 8; ++q) bsv[q] = gbin(ids[q]);
            #pragma unroll
            for (int q = 0; q < 8; ++q) {
                int slot = mc > CAP ? CAP : mc;
                slist[slot * SSTR + tid] = (uint8_t)ids[q];
                mc += (bsv[q] == storebin);
            }
        }
        for (; j < dg; ++j) {
            uint32_t id = nb[j];
            int bv = gbin(id);
            int slot = mc > CAP ? CAP : mc;
            slist[slot * SSTR + tid] = (uint8_t)id;
            mc += (bv == storebin);
        }
        if (ne >= 1) {
            int slot = mc > CAP ? CAP : mc;
            slist[slot * SSTR + tid] = (uint8_t)SID_PREV;
            mc += (be0 == storebin);
        }
        if (ne == 2) {
            int slot = mc > CAP ? CAP : mc;
            slist[slot * SSTR + tid] = (uint8_t)SID_NEXT;
            mc += (be1 == storebin);
        }
    }

    // band value fetch: id & 127 keeps even garbage/sentinel ids in-bounds;
    // sentinels override via cndmask. slist column tid is thread-private, so
    // no barrier needed between A2 writes and these reads (same-thread lgkmcnt).
    auto bandval = [&](int e) -> float {
        uint32_t id = slist[e * SSTR + tid];
        float v = sval[(id & 127u) * DD + d];
        v = (id == SID_PREV) ? exv0 : v;
        v = (id == SID_NEXT) ? exv1 : v;
        return v;
    };

    // ---- B: single W=16 counting pass over the band (mc <= CAP) ----
    float ki[CAP];
    uint32_t cn[CAP];
    #pragma unroll
    for (int u = 0; u < CAP; ++u) {
        float v = bandval(u);
        ki[u] = (u < mc) ? v : INFV;
        cn[u] = 0;
    }
    int mm = mc;  // wave max -> uniform trip count
    #pragma unroll
    for (int off = 32; off; off >>= 1) {
        int o = __shfl_xor(mm, off);
        mm = mm > o ? mm : o;
    }
    {
        int j = 0;
        for (; j + 2 <= mm; j += 2) {  // unroll 2: two independent LDS chains
            float x0 = bandval(j);
            float x1 = bandval(j + 1);
            x0 = (j < mc) ? x0 : INFV;      // INF < ki never true
            x1 = (j + 1 < mc) ? x1 : INFV;
            #pragma unroll
            for (int u = 0; u < CAP; ++u) cn[u] += (x0 < ki[u]) + (x1 < ki[u]);
        }
        if (j < mm) {
            float x = bandval(j);
            x = (j < mc) ? x : INFV;
            #pragma unroll
            for (int u = 0; u < CAP; ++u) cn[u] += (x < ki[u]);
        }
    }
    float result = 0.0f;
    bool found = fb;
    #pragma unroll
    for (int u = 0; u < CAP; ++u) {
        // strict-below count == rp identifies rank-rp exactly (unique per value)
        if (!found && u < mc && cn[u] == rp) { result = ki[u]; found = true; }
    }

    // ---- duplicate-median pass (exact multiset lower-median; ~never runs) ----
    if (__ballot(!found)) {
        uint32_t eq[CAP];
        #pragma unroll
        for (int u = 0; u < CAP; ++u) eq[u] = 0;
        for (int j = 0; j < mm; ++j) {
            float x = bandval(j);
            x = (j < mc) ? x : INFV;  // INF == finite ki is false
            #pragma unroll
            for (int u = 0; u < CAP; ++u) eq[u] += (x == ki[u]);
        }
        #pragma unroll
        for (int u = 0; u < CAP; ++u) {
            if (!found && u < mc && cn[u] <= rp && rp < cn[u] + eq[u]) {
                result = ki[u]; found = true;
            }
        }
    }

    // ---- full fallback (band > CAP; ~1e-5 of lanes): exact over all k ----
    if (__ballot(fb)) {
        bool done = !fb;
        for (int i0 = 0; __ballot(!done && i0 < k); i0 += 8) {
            float k8[8]; uint32_t c8[8];
            #pragma unroll
            for (int u = 0; u < 8; ++u) {
                int i = i0 + u;
                float sv = sval[nb[i & 127] * DD + d];
                float ev = ((i - dg) == 0) ? exv0 : exv1;
                float v = (i < dg) ? sv : ev;
                k8[u] = (i < k) ? v : INFV;
                c8[u] = 0;
            }
            for (int j = 0; j < dg; ++j) {
                float xv = sval[nb[j] * DD + d];
                #pragma unroll
                for (int u = 0; u < 8; ++u) c8[u] += (xv < k8[u]);
            }
            if (ne >= 1) {
                #pragma unroll
                for (int u = 0; u < 8; ++u) c8[u] += (exv0 < k8[u]);
            }
            if (ne == 2) {
                #pragma unroll
                for (int u = 0; u < 8; ++u) c8[u] += (exv1 < k8[u]);
            }
            #pragma unroll
            for (int u = 0; u < 8; ++u) {
                if (!done && (i0 + u) < k && c8[u] == r) { result = k8[u]; done = true; }
            }
        }
        if (__ballot(!done)) {  // duplicates across rank: exact multiset selection
            for (int i0 = 0; __ballot(!done && i0 < k); i0 += 4) {
                float k4[4]; uint32_t lt4[4], le4[4];
                #pragma unroll
                for (int u = 0; u < 4; ++u) {
                    int i = i0 + u;
                    float sv = sval[nb[i & 127] * DD + d];
                    float ev = ((i - dg) == 0) ? exv0 : exv1;
                    float v = (i < dg) ? sv : ev;
                    k4[u] = (i < k) ? v : INFV;
                    lt4[u] = 0; le4[u] = 0;
                }
                for (int j = 0; j < dg; ++j) {
                    float xv = sval[nb[j] * DD + d];
                    #pragma unroll
                    for (int u = 0; u < 4; ++u) { lt4[u] += (xv < k4[u]); le4[u] += (xv <= k4[u]); }
                }
                if (ne >= 1) {
                    #pragma unroll
                    for (int u = 0; u < 4; ++u) { lt4[u] += (exv0 < k4[u]); le4[u] += (exv0 <= k4[u]); }
                }
                if (ne == 2) {
                    #pragma unroll
                    for (int u = 0; u < 4; ++u) { lt4[u] += (exv1 < k4[u]); le4[u] += (exv1 <= k4[u]); }
                }
                #pragma unroll
                for (int u = 0; u < 4; ++u) {
                    if (!done && (i0 + u) < k && lt4[u] <= r && r < le4[u]) {
                        result = k4[u]; done = true;
                    }
                }
            }
        }
    }

    out[(((size_t)(b * TT + t) * NN) + n) * DD + d] = result;
}

extern "C" void kernel_launch(void* const* d_in, const int* in_sizes, int n_in,
                              void* d_out, int out_size, void* d_ws, size_t ws_size,
                              hipStream_t stream) {
    const float* xs = (const float*)d_in[0];
    const int* A = (const int*)d_in[1];
    float* out = (float*)d_out;
    (void)d_ws; (void)ws_size;  // no workspace: adjacency fused into the kernel

    median_kernel<<<NBLK, TPB, 0, stream>>>(xs, A, out);
}

// Round 10
// 116.457 us; speedup vs baseline: 2.5055x; 1.0358x over previous
//
#include <hip/hip_runtime.h>
#include <stdint.h>
#include <math.h>

// Problem shape (fixed by reference): xs [B,T,N,D] fp32, A [1,N,N] int32
#define BB 4
#define TT 32
#define NN 128
#define DD 32
#define NPB 16                       // nodes per block (16 nodes x 32 d = 512 threads)
#define TPB (NPB * DD)               // 512 threads
#define NBLK (BB * TT * (NN / NPB))  // 1024 blocks = exactly 4 per CU
#define CAP 16                       // band list capacity; selected-bin overflow -> exact fallback
#define SSTR (TPB + 4)               // 516: slist column stride (scatters banks across slots)

// Temporal-candidate sentinel ids in the u8 band list (real ids are 0..127).
#define SID_PREV 0xFEu
#define SID_NEXT 0xFFu

// Arithmetic 8-bin partition of the value axis. ANY monotone non-decreasing
// bin function gives exact rank selection (equal values -> equal bins, so
// bins partition the multiset in value order). Median of ~66 N(0,1) lands in
// a bin with count <= CAP except ~1e-5/lane -> fallback is exact anyway.
__device__ __forceinline__ int bin8(float x) {
    int i = (int)fmaf(x, 5.0f, 4.0f);   // trunc; monotone non-decreasing
    i = i < 0 ? 0 : i;
    return i > 7 ? 7 : i;
}

// R10: bisection step 2. R9 proved bitplane A1 healthy (83.7 -> 76.5us), so
// the R4/R5 curse (250us) lives in {ffs-walk extraction, all-pairs ranking}.
// This round: A2's 66-candidate scan (66 byte-reads + 66 stores + serial mc
// chain, the largest remaining phase) is replaced by a static 16-step
// ffs-walk of the band bitmask (bitplane[selbin] & adjacency) -- pure VALU,
// zero LDS in the loop, 16 byte-stores of member ids. B (slist counting
// ranking), dup pass, fallback: byte-identical to R9. Member order in slist
// changes (ascending id) -- irrelevant, ranking is counting-based.
// If this regresses >=150us, the curse is the ffs-walk itself (all-pairs
// ranking is avoided here) and R11 does rank-refinement without extraction.
__global__ __launch_bounds__(TPB) void median_kernel(const float* __restrict__ xs,
                                                     const int* __restrict__ A,
                                                     float* __restrict__ out) {
    __shared__ float sval[NN * DD];             // 16 KB: current frame values
    __shared__ uint8_t sbin[NN * DD];           // 4 KB: per-element bin (0..7)
    __shared__ __align__(16) uint32_t sbit[8 * DD * 4]; // 4 KB: bitplanes [bin][d][n/32]
    __shared__ uint32_t snbr_w[NPB * NN / 4];   // 2 KB: neighbor id lists (u8, fallback only)
    __shared__ __align__(16) uint32_t smask[NPB][4];    // 256 B: adjacency masks
    __shared__ int sdeg[NPB];
    __shared__ uint8_t slist[(CAP + 1) * SSTR]; // 8.8 KB: band member IDS, column-major

    const int tid = threadIdx.x;
    // Bijective XCD swizzle (NBLK % 8 == 0): each XCD gets a contiguous chunk
    // of 128 logical blocks = 16 whole frames -> frame re-reads are L2-local.
    const int bid = blockIdx.x;
    const int g = ((bid & 7) << 7) | (bid >> 3);
    const int ng = g & (NN / NPB - 1);       // % 8
    const int t  = (g >> 3) & (TT - 1);      // /8 % 32
    const int b  = g >> 8;                   // /256
    const int n0 = ng * NPB;

    const int d = tid & (DD - 1);
    const int nl = tid >> 5;  // local node 0..15
    const int n = n0 + nl;
    const int pv = (t > 0) ? 1 : 0;        // wave-uniform
    const int nv = (t < TT - 1) ? 1 : 0;   // wave-uniform
    const int ne = pv + nv;

    // temporal candidates as floats (coalesced; issued before the barrier)
    float exv0 = 0.0f, exv1 = 0.0f;
    if (pv) exv0 = xs[(((size_t)(b * TT + t - 1) * NN) + n) * DD + d];
    if (nv) {
        float v = xs[(((size_t)(b * TT + t + 1) * NN) + n) * DD + d];
        if (pv) exv1 = v; else exv0 = v;
    }

    // stage current frame (float4 coalesced) + per-element bins (u32-packed)
    const float4* src4 = (const float4*)(xs + ((size_t)(b * TT + t) * NN) * DD);
    #pragma unroll
    for (int s = 0; s < 2; ++s) {
        int i4 = tid + (s << 9);
        float4 f = src4[i4];
        ((float4*)sval)[i4] = f;
        uint32_t pk = (uint32_t)bin8(f.x) | ((uint32_t)bin8(f.y) << 8)
                    | ((uint32_t)bin8(f.z) << 16) | ((uint32_t)bin8(f.w) << 24);
        ((uint32_t*)sbin)[i4] = pk;
    }

    // ---- fused adjacency build: wave wid ballots rows 2*wid, 2*wid+1 of A
    // (+ implicit self loop) into compacted u8 lists AND raw mask words.
    {
        uint8_t* snbr = (uint8_t*)snbr_w;
        const int lane = tid & 63;
        const int wid = tid >> 6;  // 0..7
        const unsigned long long lmask = (1ULL << lane) - 1ULL;
        #pragma unroll
        for (int h = 0; h < 2; ++h) {
            const int rr = wid * 2 + h;          // local row 0..15
            const int nrow = n0 + rr;            // global node id
            const int* arow = A + nrow * NN;
            const bool b0 = (arow[lane] != 0) || (lane == nrow);
            const bool b1 = (arow[lane + 64] != 0) || (lane + 64 == nrow);
            const unsigned long long m0 = __ballot(b0);
            const unsigned long long m1 = __ballot(b1);
            const int c0 = __popcll(m0);
            if (b0) snbr[rr * NN + __popcll(m0 & lmask)] = (uint8_t)lane;
            if (b1) snbr[rr * NN + c0 + __popcll(m1 & lmask)] = (uint8_t)(lane + 64);
            if (lane == 0) {
                sdeg[rr] = c0 + __popcll(m1);
                smask[rr][0] = (uint32_t)m0;
                smask[rr][1] = (uint32_t)(m0 >> 32);
                smask[rr][2] = (uint32_t)m1;
                smask[rr][3] = (uint32_t)(m1 >> 32);
            }
        }
    }
    __syncthreads();  // sval/sbin/snbr/smask ready

    // ---- ownership bitplane build (R5 method): thread (rep, wo, dd) owns
    // words sbit[2rep..2rep+1][dd][wo]; 32 sbin byte reads, regs, 2 stores.
    {
        const int rep = tid >> 7;        // 0..3 -> bins {2r, 2r+1}
        const int wo  = (tid >> 5) & 3;  // word 0..3 -> nodes [wo*32, wo*32+32)
        const int dd  = tid & 31;
        const int ba = rep * 2, bc = ba + 1;
        uint32_t lo = 0u, hi = 0u;
        #pragma unroll 8
        for (int q = 0; q < 32; ++q) {
            const int bv = (int)sbin[(wo * 32 + q) * DD + dd];
            lo |= (bv == ba) ? (1u << q) : 0u;
            hi |= (bv == bc) ? (1u << q) : 0u;
        }
        sbit[ba * 128 + dd * 4 + wo] = lo;
        sbit[bc * 128 + dd * 4 + wo] = hi;
    }
    __syncthreads();  // bitplanes visible

    const int dg = sdeg[nl];
    const int k = dg + ne;
    const uint32_t r = (uint32_t)((k - 1) >> 1);  // lower-median rank (0-based)
    const uint8_t* nb = (const uint8_t*)snbr_w + nl * NN;
    const float INFV = __uint_as_float(0x7F800000u);
    const int be0 = bin8(exv0);
    const int be1 = bin8(exv1);

    // ---- A1: bitplane histogram -- 8 x (b128 read, AND, popcount) ----
    const uint4 am4 = *((const uint4*)smask[nl]);  // broadcast within node-group
    int hist[8];
    const uint4* sbit4 = (const uint4*)sbit;
    #pragma unroll
    for (int bb = 0; bb < 8; ++bb) {
        uint4 w = sbit4[bb * 32 + d];
        hist[bb] = __popc(w.x & am4.x) + __popc(w.y & am4.y)
                 + __popc(w.z & am4.z) + __popc(w.w & am4.w);
    }

    // ---- prefix over bins (temporal folded in); select bin containing r ----
    uint32_t cum = 0, lowcnt = 0, mexp = 0;
    int selbin = -1;
    #pragma unroll
    for (int bb = 0; bb < 8; ++bb) {
        uint32_t bc = (uint32_t)hist[bb] + ((ne >= 1 && be0 == bb) ? 1u : 0u)
                                         + ((ne == 2 && be1 == bb) ? 1u : 0u);
        uint32_t nc = cum + bc;
        if (selbin < 0 && r < nc) { selbin = bb; lowcnt = cum; mexp = bc; }
        cum = nc;
    }
    const bool fb = (mexp > CAP);          // only fallback: band too big
    const uint32_t rp = r - lowcnt;        // rank within band
    const int storebin = fb ? -1 : selbin; // fb lanes: mc stays 0

    // ---- A2 (NEW): band member ids via static ffs-walk of the band bitmask
    // (bitplane[selbin] & adjacency). Pure-VALU 16-step walk, no LDS reads,
    // 16 u8 stores. Replaces the 66-candidate scan + serial mc chain. ----
    const int sb = fb ? 0 : selbin;
    const uint4 wsel = sbit4[sb * 32 + d];
    unsigned long long bm0 = (((unsigned long long)(wsel.y & am4.y)) << 32) | (wsel.x & am4.x);
    unsigned long long bm1 = (((unsigned long long)(wsel.w & am4.w)) << 32) | (wsel.z & am4.z);
    const int mc_sp = fb ? 0 : (__popcll(bm0) + __popcll(bm1));
    #pragma unroll
    for (int u = 0; u < CAP; ++u) {
        const bool lo = (bm0 != 0ull);
        const unsigned long long mm_ = lo ? bm0 : bm1;
        const int ff = __ffsll((unsigned long long)mm_) - 1;  // -1 when empty
        const uint32_t id = (uint32_t)((lo ? ff : 64 + ff) & 127);
        slist[u * SSTR + tid] = (uint8_t)id;   // garbage beyond mc_sp: never read
        const unsigned long long cl = mm_ & (mm_ - 1ull);
        bm0 = lo ? cl : bm0;
        bm1 = lo ? bm1 : cl;
    }
    int mc = mc_sp;
    if (ne >= 1) {
        int slot = mc > CAP ? CAP : mc;
        slist[slot * SSTR + tid] = (uint8_t)SID_PREV;
        mc += (be0 == storebin);
    }
    if (ne == 2) {
        int slot = mc > CAP ? CAP : mc;
        slist[slot * SSTR + tid] = (uint8_t)SID_NEXT;
        mc += (be1 == storebin);
    }

    // band value fetch: id & 127 keeps even garbage/sentinel ids in-bounds;
    // sentinels override via cndmask. slist column tid is thread-private, so
    // no barrier needed between A2 writes and these reads (same-thread lgkmcnt).
    auto bandval = [&](int e) -> float {
        uint32_t id = slist[e * SSTR + tid];
        float v = sval[(id & 127u) * DD + d];
        v = (id == SID_PREV) ? exv0 : v;
        v = (id == SID_NEXT) ? exv1 : v;
        return v;
    };

    // ---- B: single W=16 counting pass over the band (mc <= CAP) ----
    float ki[CAP];
    uint32_t cn[CAP];
    #pragma unroll
    for (int u = 0; u < CAP; ++u) {
        float v = bandval(u);
        ki[u] = (u < mc) ? v : INFV;
        cn[u] = 0;
    }
    int mm = mc;  // wave max -> uniform trip count
    #pragma unroll
    for (int off = 32; off; off >>= 1) {
        int o = __shfl_xor(mm, off);
        mm = mm > o ? mm : o;
    }
    {
        int j = 0;
        for (; j + 2 <= mm; j += 2) {  // unroll 2: two independent LDS chains
            float x0 = bandval(j);
            float x1 = bandval(j + 1);
            x0 = (j < mc) ? x0 : INFV;      // INF < ki never true
            x1 = (j + 1 < mc) ? x1 : INFV;
            #pragma unroll
            for (int u = 0; u < CAP; ++u) cn[u] += (x0 < ki[u]) + (x1 < ki[u]);
        }
        if (j < mm) {
            float x = bandval(j);
            x = (j < mc) ? x : INFV;
            #pragma unroll
            for (int u = 0; u < CAP; ++u) cn[u] += (x < ki[u]);
        }
    }
    float result = 0.0f;
    bool found = fb;
    #pragma unroll
    for (int u = 0; u < CAP; ++u) {
        // strict-below count == rp identifies rank-rp exactly (unique per value)
        if (!found && u < mc && cn[u] == rp) { result = ki[u]; found = true; }
    }

    // ---- duplicate-median pass (exact multiset lower-median; ~never runs) ----
    if (__ballot(!found)) {
        uint32_t eq[CAP];
        #pragma unroll
        for (int u = 0; u < CAP; ++u) eq[u] = 0;
        for (int j = 0; j < mm; ++j) {
            float x = bandval(j);
            x = (j < mc) ? x : INFV;  // INF == finite ki is false
            #pragma unroll
            for (int u = 0; u < CAP; ++u) eq[u] += (x == ki[u]);
        }
        #pragma unroll
        for (int u = 0; u < CAP; ++u) {
            if (!found && u < mc && cn[u] <= rp && rp < cn[u] + eq[u]) {
                result = ki[u]; found = true;
            }
        }
    }

    // ---- full fallback (band > CAP; ~1e-5 of lanes): exact over all k ----
    if (__ballot(fb)) {
        bool done = !fb;
        for (int i0 = 0; __ballot(!done && i0 < k); i0 += 8) {
            float k8[8]; uint32_t c8[8];
            #pragma unroll
            for (int u = 0; u < 8; ++u) {
                int i = i0 + u;
                float sv = sval[nb[i & 127] * DD + d];
                float ev = ((i - dg) == 0) ? exv0 : exv1;
                float v = (i < dg) ? sv : ev;
                k8[u] = (i < k) ? v : INFV;
                c8[u] = 0;
            }
            for (int j = 0; j < dg; ++j) {
                float xv = sval[nb[j] * DD + d];
                #pragma unroll
                for (int u = 0; u < 8; ++u) c8[u] += (xv < k8[u]);
            }
            if (ne >= 1) {
                #pragma unroll
                for (int u = 0; u < 8; ++u) c8[u] += (exv0 < k8[u]);
            }
            if (ne == 2) {
                #pragma unroll
                for (int u = 0; u < 8; ++u) c8[u] += (exv1 < k8[u]);
            }
            #pragma unroll
            for (int u = 0; u < 8; ++u) {
                if (!done && (i0 + u) < k && c8[u] == r) { result = k8[u]; done = true; }
            }
        }
        if (__ballot(!done)) {  // duplicates across rank: exact multiset selection
            for (int i0 = 0; __ballot(!done && i0 < k); i0 += 4) {
                float k4[4]; uint32_t lt4[4], le4[4];
                #pragma unroll
                for (int u = 0; u < 4; ++u) {
                    int i = i0 + u;
                    float sv = sval[nb[i & 127] * DD + d];
                    float ev = ((i - dg) == 0) ? exv0 : exv1;
                    float v = (i < dg) ? sv : ev;
                    k4[u] = (i < k) ? v : INFV;
                    lt4[u] = 0; le4[u] = 0;
                }
                for (int j = 0; j < dg; ++j) {
                    float xv = sval[nb[j] * DD + d];
                    #pragma unroll
                    for (int u = 0; u < 4; ++u) { lt4[u] += (xv < k4[u]); le4[u] += (xv <= k4[u]); }
                }
                if (ne >= 1) {
                    #pragma unroll
                    for (int u = 0; u < 4; ++u) { lt4[u] += (exv0 < k4[u]); le4[u] += (exv0 <= k4[u]); }
                }
                if (ne == 2) {
                    #pragma unroll
                    for (int u = 0; u < 4; ++u) { lt4[u] += (exv1 < k4[u]); le4[u] += (exv1 <= k4[u]); }
                }
                #pragma unroll
                for (int u = 0; u < 4; ++u) {
                    if (!done && (i0 + u) < k && lt4[u] <= r && r < le4[u]) {
                        result = k4[u]; done = true;
                    }
                }
            }
        }
    }

    out[(((size_t)(b * TT + t) * NN) + n) * DD + d] = result;
}

extern "C" void kernel_launch(void* const* d_in, const int* in_sizes, int n_in,
                              void* d_out, int out_size, void* d_ws, size_t ws_size,
                              hipStream_t stream) {
    const float* xs = (const float*)d_in[0];
    const int* A = (const int*)d_in[1];
    float* out = (float*)d_out;
    (void)d_ws; (void)ws_size;  // no workspace: adjacency fused into the kernel

    median_kernel<<<NBLK, TPB, 0, stream>>>(xs, A, out);
}

// Round 11
// 110.108 us; speedup vs baseline: 2.6500x; 1.0577x over previous
//
#include <hip/hip_runtime.h>
#include <stdint.h>
#include <math.h>

// Problem shape (fixed by reference): xs [B,T,N,D] fp32, A [1,N,N] int32
#define BB 4
#define TT 32
#define NN 128
#define DD 32
#define NPB 16                       // nodes per block (16 nodes x 32 d = 512 threads)
#define TPB (NPB * DD)               // 512 threads
#define NBLK (BB * TT * (NN / NPB))  // 1024 blocks = exactly 4 per CU
#define CAP 16                       // band capacity; selected-bin overflow -> exact fallback
#define NK (CAP + 2)                 // 16 spatial slots + 2 temporal slots

// Arithmetic 8-bin partition of the value axis. ANY monotone non-decreasing
// bin function gives exact rank selection (equal values -> equal bins, so
// bins partition the multiset in value order). Median of ~66 N(0,1) lands in
// a bin with count <= CAP except ~1e-5/lane -> fallback is exact anyway.
__device__ __forceinline__ int bin8(float x) {
    int i = (int)fmaf(x, 5.0f, 4.0f);   // trunc; monotone non-decreasing
    i = i < 0 ? 0 : i;
    return i > 7 ? 7 : i;
}

// R11: bisection step 3 (final component). R9 certified bitplane A1
// (76.5us), R10 certified the ffs-walk (+5.5us, NOT the R4/R5 curse).
// The only R4/R5 component still untested in the healthy lineage is the
// all-pairs in-register ranking. This round adopts it AND banks the win:
// walk ids into a static register array, gather band values with 16
// independent conflict-free sval reads (bank == d for any id), delete
// slist + B's ~50 LDS reads, rank via static 18x18 all-pairs compares.
// Healthy -> ~70-76us and the R4/R5 250us was an emergent/codegen effect;
// sick (>=150us) -> curse = all-pairs codegen, revert B to R10 slist form.
__global__ __launch_bounds__(TPB) void median_kernel(const float* __restrict__ xs,
                                                     const int* __restrict__ A,
                                                     float* __restrict__ out) {
    __shared__ float sval[NN * DD];             // 16 KB: current frame values
    __shared__ uint8_t sbin[NN * DD];           // 4 KB: per-element bin (0..7)
    __shared__ __align__(16) uint32_t sbit[8 * DD * 4]; // 4 KB: bitplanes [bin][d][n/32]
    __shared__ uint32_t snbr_w[NPB * NN / 4];   // 2 KB: neighbor id lists (u8, fallback only)
    __shared__ __align__(16) uint32_t smask[NPB][4];    // 256 B: adjacency masks
    __shared__ int sdeg[NPB];

    const int tid = threadIdx.x;
    // Bijective XCD swizzle (NBLK % 8 == 0): each XCD gets a contiguous chunk
    // of 128 logical blocks = 16 whole frames -> frame re-reads are L2-local.
    const int bid = blockIdx.x;
    const int g = ((bid & 7) << 7) | (bid >> 3);
    const int ng = g & (NN / NPB - 1);       // % 8
    const int t  = (g >> 3) & (TT - 1);      // /8 % 32
    const int b  = g >> 8;                   // /256
    const int n0 = ng * NPB;

    const int d = tid & (DD - 1);
    const int nl = tid >> 5;  // local node 0..15
    const int n = n0 + nl;
    const int pv = (t > 0) ? 1 : 0;        // wave-uniform
    const int nv = (t < TT - 1) ? 1 : 0;   // wave-uniform
    const int ne = pv + nv;

    // temporal candidates as floats (coalesced; issued before the barrier)
    float exv0 = 0.0f, exv1 = 0.0f;
    if (pv) exv0 = xs[(((size_t)(b * TT + t - 1) * NN) + n) * DD + d];
    if (nv) {
        float v = xs[(((size_t)(b * TT + t + 1) * NN) + n) * DD + d];
        if (pv) exv1 = v; else exv0 = v;
    }

    // stage current frame (float4 coalesced) + per-element bins (u32-packed)
    const float4* src4 = (const float4*)(xs + ((size_t)(b * TT + t) * NN) * DD);
    #pragma unroll
    for (int s = 0; s < 2; ++s) {
        int i4 = tid + (s << 9);
        float4 f = src4[i4];
        ((float4*)sval)[i4] = f;
        uint32_t pk = (uint32_t)bin8(f.x) | ((uint32_t)bin8(f.y) << 8)
                    | ((uint32_t)bin8(f.z) << 16) | ((uint32_t)bin8(f.w) << 24);
        ((uint32_t*)sbin)[i4] = pk;
    }

    // ---- fused adjacency build: wave wid ballots rows 2*wid, 2*wid+1 of A
    // (+ implicit self loop) into compacted u8 lists AND raw mask words.
    {
        uint8_t* snbr = (uint8_t*)snbr_w;
        const int lane = tid & 63;
        const int wid = tid >> 6;  // 0..7
        const unsigned long long lmask = (1ULL << lane) - 1ULL;
        #pragma unroll
        for (int h = 0; h < 2; ++h) {
            const int rr = wid * 2 + h;          // local row 0..15
            const int nrow = n0 + rr;            // global node id
            const int* arow = A + nrow * NN;
            const bool b0 = (arow[lane] != 0) || (lane == nrow);
            const bool b1 = (arow[lane + 64] != 0) || (lane + 64 == nrow);
            const unsigned long long m0 = __ballot(b0);
            const unsigned long long m1 = __ballot(b1);
            const int c0 = __popcll(m0);
            if (b0) snbr[rr * NN + __popcll(m0 & lmask)] = (uint8_t)lane;
            if (b1) snbr[rr * NN + c0 + __popcll(m1 & lmask)] = (uint8_t)(lane + 64);
            if (lane == 0) {
                sdeg[rr] = c0 + __popcll(m1);
                smask[rr][0] = (uint32_t)m0;
                smask[rr][1] = (uint32_t)(m0 >> 32);
                smask[rr][2] = (uint32_t)m1;
                smask[rr][3] = (uint32_t)(m1 >> 32);
            }
        }
    }
    __syncthreads();  // sval/sbin/snbr/smask ready

    // ---- ownership bitplane build (R5 method): thread (rep, wo, dd) owns
    // words sbit[2rep..2rep+1][dd][wo]; 32 sbin byte reads, regs, 2 stores.
    {
        const int rep = tid >> 7;        // 0..3 -> bins {2r, 2r+1}
        const int wo  = (tid >> 5) & 3;  // word 0..3 -> nodes [wo*32, wo*32+32)
        const int dd  = tid & 31;
        const int ba = rep * 2, bc = ba + 1;
        uint32_t lo = 0u, hi = 0u;
        #pragma unroll 8
        for (int q = 0; q < 32; ++q) {
            const int bv = (int)sbin[(wo * 32 + q) * DD + dd];
            lo |= (bv == ba) ? (1u << q) : 0u;
            hi |= (bv == bc) ? (1u << q) : 0u;
        }
        sbit[ba * 128 + dd * 4 + wo] = lo;
        sbit[bc * 128 + dd * 4 + wo] = hi;
    }
    __syncthreads();  // bitplanes visible

    const int dg = sdeg[nl];
    const int k = dg + ne;
    const uint32_t r = (uint32_t)((k - 1) >> 1);  // lower-median rank (0-based)
    const uint8_t* nb = (const uint8_t*)snbr_w + nl * NN;
    const float INFV = __uint_as_float(0x7F800000u);
    const int be0 = bin8(exv0);
    const int be1 = bin8(exv1);

    // ---- A1: bitplane histogram -- 8 x (b128 read, AND, popcount) ----
    const uint4 am4 = *((const uint4*)smask[nl]);  // broadcast within node-group
    int hist[8];
    const uint4* sbit4 = (const uint4*)sbit;
    #pragma unroll
    for (int bb = 0; bb < 8; ++bb) {
        uint4 w = sbit4[bb * 32 + d];
        hist[bb] = __popc(w.x & am4.x) + __popc(w.y & am4.y)
                 + __popc(w.z & am4.z) + __popc(w.w & am4.w);
    }

    // ---- prefix over bins (temporal folded in); select bin containing r ----
    uint32_t cum = 0, lowcnt = 0, mexp = 0;
    int selbin = -1;
    #pragma unroll
    for (int bb = 0; bb < 8; ++bb) {
        uint32_t bc = (uint32_t)hist[bb] + ((ne >= 1 && be0 == bb) ? 1u : 0u)
                                         + ((ne == 2 && be1 == bb) ? 1u : 0u);
        uint32_t nc = cum + bc;
        if (selbin < 0 && r < nc) { selbin = bb; lowcnt = cum; mexp = bc; }
        cum = nc;
    }
    const bool fb = (mexp > CAP);   // band too big -> exact fallback (~never)
    const uint32_t rp = r - lowcnt; // rank within band

    // ---- A2: static ffs-walk of the band bitmask -> id register array ----
    const int sb = fb ? 0 : selbin;
    const uint4 wsel = sbit4[sb * 32 + d];
    unsigned long long bm0 = (((unsigned long long)(wsel.y & am4.y)) << 32) | (wsel.x & am4.x);
    unsigned long long bm1 = (((unsigned long long)(wsel.w & am4.w)) << 32) | (wsel.z & am4.z);
    const int mc_sp = fb ? 0 : (__popcll(bm0) + __popcll(bm1));
    int ids[CAP];
    #pragma unroll
    for (int u = 0; u < CAP; ++u) {
        const bool lo = (bm0 != 0ull);
        const unsigned long long mm_ = lo ? bm0 : bm1;
        const int ff = __ffsll((unsigned long long)mm_) - 1;  // -1 when empty
        ids[u] = (lo ? ff : 64 + ff) & 127;                   // in-bounds always
        const unsigned long long cl = mm_ & (mm_ - 1ull);
        bm0 = lo ? cl : bm0;
        bm1 = lo ? bm1 : cl;
    }

    // ---- gather band values: 16 independent sval reads, bank == d for ANY
    // id (addr = id*32+d) -> conflict-free by construction ----
    float ki[NK];
    #pragma unroll
    for (int u = 0; u < CAP; ++u)
        ki[u] = (u < mc_sp) ? sval[ids[u] * DD + d] : INFV;
    const bool t0 = (ne >= 1) && (be0 == selbin) && !fb;
    const bool t1 = (ne == 2) && (be1 == selbin) && !fb;
    ki[CAP]     = t0 ? exv0 : INFV;
    ki[CAP + 1] = t1 ? exv1 : INFV;

    // ---- rank within band: static all-pairs strict-less in registers ----
    // (INF slots contribute 0 to finite counts; invalid slots never selected)
    float result = 0.0f;
    bool found = fb;
    #pragma unroll
    for (int u = 0; u < NK; ++u) {
        uint32_t cnu = 0;
        #pragma unroll
        for (int v = 0; v < NK; ++v) cnu += (ki[v] < ki[u]) ? 1u : 0u;
        const bool valid = (u < CAP) ? (u < mc_sp) : ((u == CAP) ? t0 : t1);
        if (!found && valid && cnu == rp) { result = ki[u]; found = true; }
    }

    // ---- duplicate-median pass (exact multiset lower-median; ~never runs) ----
    if (__ballot(!found)) {
        #pragma unroll
        for (int u = 0; u < NK; ++u) {
            uint32_t cnu = 0, equ = 0;
            #pragma unroll
            for (int v = 0; v < NK; ++v) {
                cnu += (ki[v] < ki[u]) ? 1u : 0u;
                equ += (ki[v] == ki[u]) ? 1u : 0u;  // includes self
            }
            const bool valid = (u < CAP) ? (u < mc_sp) : ((u == CAP) ? t0 : t1);
            if (!found && valid && cnu <= rp && rp < cnu + equ) {
                result = ki[u]; found = true;
            }
        }
    }

    // ---- full fallback (band > CAP; ~1e-5 of lanes): exact over all k ----
    if (__ballot(fb)) {
        bool done = !fb;
        for (int i0 = 0; __ballot(!done && i0 < k); i0 += 8) {
            float k8[8]; uint32_t c8[8];
            #pragma unroll
            for (int u = 0; u < 8; ++u) {
                int i = i0 + u;
                float sv = sval[nb[i & 127] * DD + d];
                float ev = ((i - dg) == 0) ? exv0 : exv1;
                float v = (i < dg) ? sv : ev;
                k8[u] = (i < k) ? v : INFV;
                c8[u] = 0;
            }
            for (int j = 0; j < dg; ++j) {
                float xv = sval[nb[j] * DD + d];
                #pragma unroll
                for (int u = 0; u < 8; ++u) c8[u] += (xv < k8[u]);
            }
            if (ne >= 1) {
                #pragma unroll
                for (int u = 0; u < 8; ++u) c8[u] += (exv0 < k8[u]);
            }
            if (ne == 2) {
                #pragma unroll
                for (int u = 0; u < 8; ++u) c8[u] += (exv1 < k8[u]);
            }
            #pragma unroll
            for (int u = 0; u < 8; ++u) {
                if (!done && (i0 + u) < k && c8[u] == r) { result = k8[u]; done = true; }
            }
        }
        if (__ballot(!done)) {  // duplicates across rank: exact multiset selection
            for (int i0 = 0; __ballot(!done && i0 < k); i0 += 4) {
                float k4[4]; uint32_t lt4[4], le4[4];
                #pragma unroll
                for (int u = 0; u < 4; ++u) {
                    int i = i0 + u;
                    float sv = sval[nb[i & 127] * DD + d];
                    float ev = ((i - dg) == 0) ? exv0 : exv1;
                    float v = (i < dg) ? sv : ev;
                    k4[u] = (i < k) ? v : INFV;
                    lt4[u] = 0; le4[u] = 0;
                }
                for (int j = 0; j < dg; ++j) {
                    float xv = sval[nb[j] * DD + d];
                    #pragma unroll
                    for (int u = 0; u < 4; ++u) { lt4[u] += (xv < k4[u]); le4[u] += (xv <= k4[u]); }
                }
                if (ne >= 1) {
                    #pragma unroll
                    for (int u = 0; u < 4; ++u) { lt4[u] += (exv0 < k4[u]); le4[u] += (exv0 <= k4[u]); }
                }
                if (ne == 2) {
                    #pragma unroll
                    for (int u = 0; u < 4; ++u) { lt4[u] += (exv1 < k4[u]); le4[u] += (exv1 <= k4[u]); }
                }
                #pragma unroll
                for (int u = 0; u < 4; ++u) {
                    if (!done && (i0 + u) < k && lt4[u] <= r && r < le4[u]) {
                        result = k4[u]; done = true;
                    }
                }
            }
        }
    }

    out[(((size_t)(b * TT + t) * NN) + n) * DD + d] = result;
}

extern "C" void kernel_launch(void* const* d_in, const int* in_sizes, int n_in,
                              void* d_out, int out_size, void* d_ws, size_t ws_size,
                              hipStream_t stream) {
    const float* xs = (const float*)d_in[0];
    const int* A = (const int*)d_in[1];
    float* out = (float*)d_out;
    (void)d_ws; (void)ws_size;  // no workspace: adjacency fused into the kernel

    median_kernel<<<NBLK, TPB, 0, stream>>>(xs, A, out);
}

// Round 12
// 110.090 us; speedup vs baseline: 2.6504x; 1.0002x over previous
//
#include <hip/hip_runtime.h>
#include <stdint.h>
#include <math.h>

// Problem shape (fixed by reference): xs [B,T,N,D] fp32, A [1,N,N] int32
#define BB 4
#define TT 32
#define NN 128
#define DD 32
#define NPB 16                       // nodes per block (16 nodes x 32 d = 512 threads)
#define TPB (NPB * DD)               // 512 threads
#define NBLK (BB * TT * (NN / NPB))  // 1024 blocks = exactly 4 per CU
#define CAP 16                       // band capacity; selected-bin overflow -> exact fallback
#define NK (CAP + 2)                 // 16 spatial slots + 2 temporal slots

// Arithmetic 8-bin partition of the value axis. ANY monotone non-decreasing
// bin function gives exact rank selection (equal values -> equal bins, so
// bins partition the multiset in value order). Median of ~66 N(0,1) lands in
// a bin with count <= CAP except ~1e-5/lane -> fallback is exact anyway.
__device__ __forceinline__ int bin8(float x) {
    int i = (int)fmaf(x, 5.0f, 4.0f);   // trunc; monotone non-decreasing
    i = i < 0 ? 0 : i;
    return i > 7 ? 7 : i;
}

// R12: antisymmetric triangular ranking. R11 closed the bisection at 65us
// (full bitset pipeline healthy; R4/R5's 250us was emergent, not any single
// construct). Largest remaining VALU block was the 18x18 all-pairs ranking
// (~650 VALU/thread, ~30% of issue). Replaced by one-compare-per-pair:
//   lt = ki[v]<ki[u]; cn[u]+=lt; cn[v]+=!lt   (153 pairs)
// This ranks by the TOTAL order (value, index) -- a valid tie-break, so
// ranks are a unique permutation and rank-rp's value is exactly the
// multiset lower median. Ties can no longer yield "no match", so the
// duplicate-median pass is provably dead and deleted, and the serial
// `found` chain is gone (unique match -> unconditional select).
// All finite values rank below INF padding; mexp >= rp+1 guarantees the
// rank-rp slot is valid. Fallback (band > CAP, ~1e-5) unchanged.
__global__ __launch_bounds__(TPB) void median_kernel(const float* __restrict__ xs,
                                                     const int* __restrict__ A,
                                                     float* __restrict__ out) {
    __shared__ float sval[NN * DD];             // 16 KB: current frame values
    __shared__ uint8_t sbin[NN * DD];           // 4 KB: per-element bin (0..7)
    __shared__ __align__(16) uint32_t sbit[8 * DD * 4]; // 4 KB: bitplanes [bin][d][n/32]
    __shared__ uint32_t snbr_w[NPB * NN / 4];   // 2 KB: neighbor id lists (u8, fallback only)
    __shared__ __align__(16) uint32_t smask[NPB][4];    // 256 B: adjacency masks
    __shared__ int sdeg[NPB];

    const int tid = threadIdx.x;
    // Bijective XCD swizzle (NBLK % 8 == 0): each XCD gets a contiguous chunk
    // of 128 logical blocks = 16 whole frames -> frame re-reads are L2-local.
    const int bid = blockIdx.x;
    const int g = ((bid & 7) << 7) | (bid >> 3);
    const int ng = g & (NN / NPB - 1);       // % 8
    const int t  = (g >> 3) & (TT - 1);      // /8 % 32
    const int b  = g >> 8;                   // /256
    const int n0 = ng * NPB;

    const int d = tid & (DD - 1);
    const int nl = tid >> 5;  // local node 0..15
    const int n = n0 + nl;
    const int pv = (t > 0) ? 1 : 0;        // wave-uniform
    const int nv = (t < TT - 1) ? 1 : 0;   // wave-uniform
    const int ne = pv + nv;

    // temporal candidates as floats (coalesced; issued before the barrier)
    float exv0 = 0.0f, exv1 = 0.0f;
    if (pv) exv0 = xs[(((size_t)(b * TT + t - 1) * NN) + n) * DD + d];
    if (nv) {
        float v = xs[(((size_t)(b * TT + t + 1) * NN) + n) * DD + d];
        if (pv) exv1 = v; else exv0 = v;
    }

    // stage current frame (float4 coalesced) + per-element bins (u32-packed)
    const float4* src4 = (const float4*)(xs + ((size_t)(b * TT + t) * NN) * DD);
    #pragma unroll
    for (int s = 0; s < 2; ++s) {
        int i4 = tid + (s << 9);
        float4 f = src4[i4];
        ((float4*)sval)[i4] = f;
        uint32_t pk = (uint32_t)bin8(f.x) | ((uint32_t)bin8(f.y) << 8)
                    | ((uint32_t)bin8(f.z) << 16) | ((uint32_t)bin8(f.w) << 24);
        ((uint32_t*)sbin)[i4] = pk;
    }

    // ---- fused adjacency build: wave wid ballots rows 2*wid, 2*wid+1 of A
    // (+ implicit self loop) into compacted u8 lists AND raw mask words.
    {
        uint8_t* snbr = (uint8_t*)snbr_w;
        const int lane = tid & 63;
        const int wid = tid >> 6;  // 0..7
        const unsigned long long lmask = (1ULL << lane) - 1ULL;
        #pragma unroll
        for (int h = 0; h < 2; ++h) {
            const int rr = wid * 2 + h;          // local row 0..15
            const int nrow = n0 + rr;            // global node id
            const int* arow = A + nrow * NN;
            const bool b0 = (arow[lane] != 0) || (lane == nrow);
            const bool b1 = (arow[lane + 64] != 0) || (lane + 64 == nrow);
            const unsigned long long m0 = __ballot(b0);
            const unsigned long long m1 = __ballot(b1);
            const int c0 = __popcll(m0);
            if (b0) snbr[rr * NN + __popcll(m0 & lmask)] = (uint8_t)lane;
            if (b1) snbr[rr * NN + c0 + __popcll(m1 & lmask)] = (uint8_t)(lane + 64);
            if (lane == 0) {
                sdeg[rr] = c0 + __popcll(m1);
                smask[rr][0] = (uint32_t)m0;
                smask[rr][1] = (uint32_t)(m0 >> 32);
                smask[rr][2] = (uint32_t)m1;
                smask[rr][3] = (uint32_t)(m1 >> 32);
            }
        }
    }
    __syncthreads();  // sval/sbin/snbr/smask ready

    // ---- ownership bitplane build (R5 method): thread (rep, wo, dd) owns
    // words sbit[2rep..2rep+1][dd][wo]; 32 sbin byte reads, regs, 2 stores.
    {
        const int rep = tid >> 7;        // 0..3 -> bins {2r, 2r+1}
        const int wo  = (tid >> 5) & 3;  // word 0..3 -> nodes [wo*32, wo*32+32)
        const int dd  = tid & 31;
        const int ba = rep * 2, bc = ba + 1;
        uint32_t lo = 0u, hi = 0u;
        #pragma unroll 8
        for (int q = 0; q < 32; ++q) {
            const int bv = (int)sbin[(wo * 32 + q) * DD + dd];
            lo |= (bv == ba) ? (1u << q) : 0u;
            hi |= (bv == bc) ? (1u << q) : 0u;
        }
        sbit[ba * 128 + dd * 4 + wo] = lo;
        sbit[bc * 128 + dd * 4 + wo] = hi;
    }
    __syncthreads();  // bitplanes visible

    const int dg = sdeg[nl];
    const int k = dg + ne;
    const uint32_t r = (uint32_t)((k - 1) >> 1);  // lower-median rank (0-based)
    const uint8_t* nb = (const uint8_t*)snbr_w + nl * NN;
    const float INFV = __uint_as_float(0x7F800000u);
    const int be0 = bin8(exv0);
    const int be1 = bin8(exv1);

    // ---- A1: bitplane histogram -- 8 x (b128 read, AND, popcount) ----
    const uint4 am4 = *((const uint4*)smask[nl]);  // broadcast within node-group
    int hist[8];
    const uint4* sbit4 = (const uint4*)sbit;
    #pragma unroll
    for (int bb = 0; bb < 8; ++bb) {
        uint4 w = sbit4[bb * 32 + d];
        hist[bb] = __popc(w.x & am4.x) + __popc(w.y & am4.y)
                 + __popc(w.z & am4.z) + __popc(w.w & am4.w);
    }

    // ---- prefix over bins (temporal folded in); select bin containing r ----
    uint32_t cum = 0, lowcnt = 0, mexp = 0;
    int selbin = -1;
    #pragma unroll
    for (int bb = 0; bb < 8; ++bb) {
        uint32_t bc = (uint32_t)hist[bb] + ((ne >= 1 && be0 == bb) ? 1u : 0u)
                                         + ((ne == 2 && be1 == bb) ? 1u : 0u);
        uint32_t nc = cum + bc;
        if (selbin < 0 && r < nc) { selbin = bb; lowcnt = cum; mexp = bc; }
        cum = nc;
    }
    const bool fb = (mexp > CAP);   // band too big -> exact fallback (~never)
    const uint32_t rp = r - lowcnt; // rank within band

    // ---- A2: static ffs-walk of the band bitmask -> id register array ----
    const int sb = fb ? 0 : selbin;
    const uint4 wsel = sbit4[sb * 32 + d];
    unsigned long long bm0 = (((unsigned long long)(wsel.y & am4.y)) << 32) | (wsel.x & am4.x);
    unsigned long long bm1 = (((unsigned long long)(wsel.w & am4.w)) << 32) | (wsel.z & am4.z);
    const int mc_sp = fb ? 0 : (__popcll(bm0) + __popcll(bm1));
    int ids[CAP];
    #pragma unroll
    for (int u = 0; u < CAP; ++u) {
        const bool lo = (bm0 != 0ull);
        const unsigned long long mm_ = lo ? bm0 : bm1;
        const int ff = __ffsll((unsigned long long)mm_) - 1;  // -1 when empty
        ids[u] = (lo ? ff : 64 + ff) & 127;                   // in-bounds always
        const unsigned long long cl = mm_ & (mm_ - 1ull);
        bm0 = lo ? cl : bm0;
        bm1 = lo ? bm1 : cl;
    }

    // ---- gather band values: 16 independent sval reads, bank == d for ANY
    // id (addr = id*32+d) -> conflict-free by construction ----
    float ki[NK];
    #pragma unroll
    for (int u = 0; u < CAP; ++u)
        ki[u] = (u < mc_sp) ? sval[ids[u] * DD + d] : INFV;
    const bool t0 = (ne >= 1) && (be0 == selbin) && !fb;
    const bool t1 = (ne == 2) && (be1 == selbin) && !fb;
    ki[CAP]     = t0 ? exv0 : INFV;
    ki[CAP + 1] = t1 ? exv1 : INFV;

    // ---- rank within band: antisymmetric triangular compares (exact).
    // One compare per unordered pair ranks by total order (value, index):
    // ranks are a unique permutation, rank-rp value == multiset lower
    // median (any tie-break gives the same sorted value at position rp).
    // INF padding ranks above all finite; mexp >= rp+1 => match is valid.
    uint32_t cn[NK];
    #pragma unroll
    for (int u = 0; u < NK; ++u) cn[u] = 0;
    #pragma unroll
    for (int u = 0; u < NK; ++u) {
        #pragma unroll
        for (int v = u + 1; v < NK; ++v) {
            const bool lt = ki[v] < ki[u];   // v strictly below u
            cn[u] += lt ? 1u : 0u;
            cn[v] += lt ? 0u : 1u;           // u below v: less OR equal (u<v)
        }
    }
    float result = 0.0f;
    #pragma unroll
    for (int u = 0; u < NK; ++u) {
        const bool valid = (u < CAP) ? (u < mc_sp) : ((u == CAP) ? t0 : t1);
        if (valid && cn[u] == rp) result = ki[u];  // unique match
    }

    // ---- full fallback (band > CAP; ~1e-5 of lanes): exact over all k ----
    if (__ballot(fb)) {
        bool done = !fb;
        for (int i0 = 0; __ballot(!done && i0 < k); i0 += 8) {
            float k8[8]; uint32_t c8[8];
            #pragma unroll
            for (int u = 0; u < 8; ++u) {
                int i = i0 + u;
                float sv = sval[nb[i & 127] * DD + d];
                float ev = ((i - dg) == 0) ? exv0 : exv1;
                float v = (i < dg) ? sv : ev;
                k8[u] = (i < k) ? v : INFV;
                c8[u] = 0;
            }
            for (int j = 0; j < dg; ++j) {
                float xv = sval[nb[j] * DD + d];
                #pragma unroll
                for (int u = 0; u < 8; ++u) c8[u] += (xv < k8[u]);
            }
            if (ne >= 1) {
                #pragma unroll
                for (int u = 0; u < 8; ++u) c8[u] += (exv0 < k8[u]);
            }
            if (ne == 2) {
                #pragma unroll
                for (int u = 0; u < 8; ++u) c8[u] += (exv1 < k8[u]);
            }
            #pragma unroll
            for (int u = 0; u < 8; ++u) {
                if (!done && (i0 + u) < k && c8[u] == r) { result = k8[u]; done = true; }
            }
        }
        if (__ballot(!done)) {  // duplicates across rank: exact multiset selection
            for (int i0 = 0; __ballot(!done && i0 < k); i0 += 4) {
                float k4[4]; uint32_t lt4[4], le4[4];
                #pragma unroll
                for (int u = 0; u < 4; ++u) {
                    int i = i0 + u;
                    float sv = sval[nb[i & 127] * DD + d];
                    float ev = ((i - dg) == 0) ? exv0 : exv1;
                    float v = (i < dg) ? sv : ev;
                    k4[u] = (i < k) ? v : INFV;
                    lt4[u] = 0; le4[u] = 0;
                }
                for (int j = 0; j < dg; ++j) {
                    float xv = sval[nb[j] * DD + d];
                    #pragma unroll
                    for (int u = 0; u < 4; ++u) { lt4[u] += (xv < k4[u]); le4[u] += (xv <= k4[u]); }
                }
                if (ne >= 1) {
                    #pragma unroll
                    for (int u = 0; u < 4; ++u) { lt4[u] += (exv0 < k4[u]); le4[u] += (exv0 <= k4[u]); }
                }
                if (ne == 2) {
                    #pragma unroll
                    for (int u = 0; u < 4; ++u) { lt4[u] += (exv1 < k4[u]); le4[u] += (exv1 <= k4[u]); }
                }
                #pragma unroll
                for (int u = 0; u < 4; ++u) {
                    if (!done && (i0 + u) < k && lt4[u] <= r && r < le4[u]) {
                        result = k4[u]; done = true;
                    }
                }
            }
        }
    }

    out[(((size_t)(b * TT + t) * NN) + n) * DD + d] = result;
}

extern "C" void kernel_launch(void* const* d_in, const int* in_sizes, int n_in,
                              void* d_out, int out_size, void* d_ws, size_t ws_size,
                              hipStream_t stream) {
    const float* xs = (const float*)d_in[0];
    const int* A = (const int*)d_in[1];
    float* out = (float*)d_out;
    (void)d_ws; (void)ws_size;  // no workspace: adjacency fused into the kernel

    median_kernel<<<NBLK, TPB, 0, stream>>>(xs, A, out);
}